// Round 2
// baseline (529.014 us; speedup 1.0000x reference)
//
#include <hip/hip_runtime.h>
#include <hip/hip_bf16.h>
#include <cstdint>
#include <cstddef>

typedef __bf16 bf16;
typedef __bf16 bf16x2 __attribute__((ext_vector_type(2)));
typedef __bf16 bf16x8 __attribute__((ext_vector_type(8)));
typedef float  f32x4  __attribute__((ext_vector_type(4)));

#define HIDDEN 2048
#define NHEADS 16
#define NKV    4
#define HD     128
#define WINDOW 512

// async global->LDS, 16B per lane; LDS dest is wave-uniform base + lane*16
__device__ __forceinline__ void gld16(const void* g, void* s) {
  __builtin_amdgcn_global_load_lds((const __attribute__((address_space(1))) void*)g,
                                   (__attribute__((address_space(3))) void*)s, 16, 0, 0);
}

__device__ __forceinline__ f32x4 mfma16(bf16x8 a, bf16x8 b, f32x4 c) {
  return __builtin_amdgcn_mfma_f32_16x16x32_bf16(a, b, c, 0, 0, 0);
}

// ---------------- cast fp32 -> bf16, 4 elems/thread -------------------------
__global__ __launch_bounds__(256) void cast_f32_bf16(const float* __restrict__ in,
                                                     bf16* __restrict__ out, int n4) {
  int i = blockIdx.x * 256 + threadIdx.x;
  if (i >= n4) return;
  f32x4 v = *(const f32x4*)(in + (size_t)i * 4);
  bf16x2 a, b;
  a[0] = (bf16)v[0]; a[1] = (bf16)v[1];
  b[0] = (bf16)v[2]; b[1] = (bf16)v[3];
  *(bf16x2*)(out + (size_t)i * 4)     = a;
  *(bf16x2*)(out + (size_t)i * 4 + 2) = b;
}

// ---------------- transpose+cast: fp32 (R x C) -> bf16 (C x R) --------------
__global__ __launch_bounds__(256) void transpose_cast(const float* __restrict__ in,
                                                      bf16* __restrict__ out, int R, int C) {
  __shared__ float tile[32][33];
  int c0 = blockIdx.x * 32, r0 = blockIdx.y * 32;
  int tx = threadIdx.x, ty = threadIdx.y;
  #pragma unroll
  for (int i = 0; i < 4; ++i)
    tile[ty + i * 8][tx] = in[(size_t)(r0 + ty + i * 8) * C + c0 + tx];
  __syncthreads();
  #pragma unroll
  for (int i = 0; i < 4; ++i)
    out[(size_t)(c0 + ty + i * 8) * R + r0 + tx] = (bf16)tile[tx][ty + i * 8];
}

// ---------------- GEMM: C(MxN) = A(MxK) * Bt(NxK)^T, bf16 in, f32 acc -------
// outMode: 0 = bf16 row-major, 1 = bf16 transposed (C^T), 2 = fp32 row-major
__device__ __forceinline__ void stage128x32(const bf16* __restrict__ A,
                                            const bf16* __restrict__ Bt,
                                            bf16* sA, bf16* sB,
                                            int m0, int n0, int K, int kt, int tid) {
  int wbase = tid & ~63;
  #pragma unroll
  for (int r = 0; r < 2; ++r) {
    int e = (r * 256 + tid) * 8;
    int row = e >> 5, col = e & 31;
    gld16(A  + (size_t)(m0 + row) * K + (size_t)kt * 32 + col,
          sA + (size_t)(r * 256 + wbase) * 8);
    gld16(Bt + (size_t)(n0 + row) * K + (size_t)kt * 32 + col,
          sB + (size_t)(r * 256 + wbase) * 8);
  }
}

__global__ __launch_bounds__(256) void gemm_bt(const bf16* __restrict__ A,
                                               const bf16* __restrict__ Bt,
                                               void* __restrict__ Cv,
                                               int M, int N, int K, int outMode) {
  __shared__ bf16 sA[2][128 * 32];
  __shared__ bf16 sB[2][128 * 32];
  int nb = N >> 7;
  int bm = (int)blockIdx.x / nb, bn = (int)blockIdx.x % nb;
  int m0 = bm << 7, n0 = bn << 7;
  int tid = threadIdx.x;
  int lane = tid & 63, w = tid >> 6;
  int li = lane & 15, g = lane >> 4, g8 = g * 8;
  int wm = w >> 1, wn = w & 1;
  f32x4 acc[4][4] = {};
  int NT = K >> 5;

  stage128x32(A, Bt, sA[0], sB[0], m0, n0, K, 0, tid);
  __syncthreads();
  for (int kt = 0; kt < NT; ++kt) {
    int cur = kt & 1;
    if (kt + 1 < NT)
      stage128x32(A, Bt, sA[cur ^ 1], sB[cur ^ 1], m0, n0, K, kt + 1, tid);
    bf16x8 af[4], bv[4];
    #pragma unroll
    for (int mt = 0; mt < 4; ++mt)
      af[mt] = *(const bf16x8*)&sA[cur][(wm * 64 + mt * 16 + li) * 32 + g8];
    #pragma unroll
    for (int nt = 0; nt < 4; ++nt)
      bv[nt] = *(const bf16x8*)&sB[cur][(wn * 64 + nt * 16 + li) * 32 + g8];
    #pragma unroll
    for (int mt = 0; mt < 4; ++mt)
      #pragma unroll
      for (int nt = 0; nt < 4; ++nt)
        acc[mt][nt] = mfma16(af[mt], bv[nt], acc[mt][nt]);
    __syncthreads();
  }
  // C/D layout: col = lane&15, row = (lane>>4)*4 + j   [m89/m91 verified]
  #pragma unroll
  for (int mt = 0; mt < 4; ++mt)
    #pragma unroll
    for (int nt = 0; nt < 4; ++nt)
      #pragma unroll
      for (int j = 0; j < 4; ++j) {
        int row = m0 + wm * 64 + mt * 16 + g * 4 + j;
        int col = n0 + wn * 64 + nt * 16 + li;
        float v = acc[mt][nt][j];
        if (outMode == 0)      ((bf16*)Cv)[(size_t)row * N + col] = (bf16)v;
        else if (outMode == 1) ((bf16*)Cv)[(size_t)col * M + row] = (bf16)v;  // C^T (Vt)
        else                   ((float*)Cv)[(size_t)row * N + col] = v;
      }
}

// ---------------- RoPE in place: X (T x heads*128), interleaved pairs -------
__global__ __launch_bounds__(256) void rope_kernel(bf16* __restrict__ X,
                                                   const int* __restrict__ pos,
                                                   int T, int heads) {
  int idx = blockIdx.x * 256 + threadIdx.x;
  int total = T * heads * 64;
  if (idx >= total) return;
  int i = idx & 63;
  int rest = idx >> 6;
  int hh = rest % heads;
  int t = rest / heads;
  float inv = expf((float)i * (-9.210340371976184f / 64.0f)); // theta^(-i/64)
  float ang = (float)pos[t] * inv;
  float s, c;
  sincosf(ang, &s, &c);
  bf16* p = X + ((size_t)t * heads + hh) * HD + 2 * i;
  bf16x2 xv = *(const bf16x2*)p;
  float xe = (float)xv[0], xo = (float)xv[1];
  bf16x2 r;
  r[0] = (bf16)(xe * c - xo * s);
  r[1] = (bf16)(xe * s + xo * c);
  *(bf16x2*)p = r;
}

// ---------------- sliding-window GQA flash attention ------------------------
// grid: (T/64)*16 blocks; 4 waves/block, each wave owns 16 q rows.
// O may alias Q: each block writes exactly the (rows, head-slice) it reads,
// and Q is register-resident before any write.
__global__ __launch_bounds__(256) void attn_kernel(const bf16* __restrict__ Q,
                                                   const bf16* __restrict__ Kb,
                                                   const bf16* __restrict__ Vt,
                                                   const int* __restrict__ pos,
                                                   const int* __restrict__ cu,
                                                   bf16* __restrict__ O, int T, int B) {
  __shared__ bf16 sK[32 * 128];    // [key][d] for this kv head
  __shared__ bf16 sVt[128 * 32];   // [d][key]
  __shared__ bf16 sP[4][16 * 32];  // per-wave P tile
  int bid = blockIdx.x;
  int h  = bid & (NHEADS - 1);
  int qb = bid >> 4;
  int q0 = qb * 64;
  int kvh = h >> 2;  // 16 heads -> 4 kv heads
  int tid = threadIdx.x, lane = tid & 63, w = tid >> 6;
  int li = lane & 15, g = lane >> 4, g8 = g * 8;
  int qw0 = q0 + w * 16;

  int seq_start = 0, seq_end = T;
  for (int b = 0; b < B; ++b) {
    int a = cu[b], e = cu[b + 1];
    if (q0 >= a && q0 < e) { seq_start = a; seq_end = e; }
  }

  // Q fragments: A-layout row=lane&15, k=(lane>>4)*8+j
  bf16x8 qf[4];
  #pragma unroll
  for (int kd = 0; kd < 4; ++kd)
    qf[kd] = *(const bf16x8*)(Q + (size_t)(qw0 + li) * HIDDEN + h * HD + kd * 32 + g8);

  int pq[4];
  #pragma unroll
  for (int j = 0; j < 4; ++j) pq[j] = pos[qw0 + g * 4 + j];
  int pqw_min = pos[qw0], pqw_max = pos[qw0 + 15];

  float m_[4] = {-1e30f, -1e30f, -1e30f, -1e30f};
  float l_[4] = {0.f, 0.f, 0.f, 0.f};
  f32x4 acc[8] = {};

  int kstart = q0 - WINDOW;
  if (kstart < seq_start) kstart = seq_start;
  int kend = q0 + 64;
  if (kend > seq_end) kend = seq_end;
  const float scale = 0.08838834764831845f;  // 1/sqrt(128)

  for (int kb = kstart; kb < kend; kb += 32) {
    int wbase = tid & ~63;
    #pragma unroll
    for (int r = 0; r < 2; ++r) {
      int e = (r * 256 + tid) * 8;
      gld16(Kb + (size_t)(kb + (e >> 7)) * (NKV * HD) + kvh * HD + (e & 127),
            sK + (size_t)(r * 256 + wbase) * 8);
      gld16(Vt + (size_t)(kvh * HD + (e >> 5)) * T + kb + (e & 31),
            sVt + (size_t)(r * 256 + wbase) * 8);
    }
    __syncthreads();

    int pkf = pos[kb], pkl = pos[kb + 31];
    bool active = !(pkf > pqw_max || pkl < pqw_min - WINDOW);
    if (active) {
      f32x4 s0v = {0.f, 0.f, 0.f, 0.f}, s1v = {0.f, 0.f, 0.f, 0.f};
      #pragma unroll
      for (int kd = 0; kd < 4; ++kd) {
        bf16x8 b0 = *(const bf16x8*)&sK[(li) * 128 + kd * 32 + g8];
        bf16x8 b1 = *(const bf16x8*)&sK[(16 + li) * 128 + kd * 32 + g8];
        s0v = mfma16(qf[kd], b0, s0v);
        s1v = mfma16(qf[kd], b1, s1v);
      }
      int pk0 = pos[kb + li], pk1 = pos[kb + 16 + li];
      float alpha[4];
      #pragma unroll
      for (int j = 0; j < 4; ++j) {
        int d0 = pq[j] - pk0, d1 = pq[j] - pk1;
        float sv0 = (d0 >= 0 && d0 <= WINDOW) ? s0v[j] * scale : -1e30f;
        float sv1 = (d1 >= 0 && d1 <= WINDOW) ? s1v[j] * scale : -1e30f;
        float r = fmaxf(sv0, sv1);
        r = fmaxf(r, __shfl_xor(r, 1));
        r = fmaxf(r, __shfl_xor(r, 2));
        r = fmaxf(r, __shfl_xor(r, 4));
        r = fmaxf(r, __shfl_xor(r, 8));
        float mn = fmaxf(m_[j], r);
        alpha[j] = __expf(m_[j] - mn);
        float p0 = sv0 > -1e29f ? __expf(sv0 - mn) : 0.f;
        float p1 = sv1 > -1e29f ? __expf(sv1 - mn) : 0.f;
        float rs = p0 + p1;
        rs += __shfl_xor(rs, 1);
        rs += __shfl_xor(rs, 2);
        rs += __shfl_xor(rs, 4);
        rs += __shfl_xor(rs, 8);
        l_[j] = l_[j] * alpha[j] + rs;
        m_[j] = mn;
        sP[w][(g * 4 + j) * 32 + li]      = (bf16)p0;
        sP[w][(g * 4 + j) * 32 + 16 + li] = (bf16)p1;
      }
      #pragma unroll
      for (int dt = 0; dt < 8; ++dt) {
        acc[dt][0] *= alpha[0]; acc[dt][1] *= alpha[1];
        acc[dt][2] *= alpha[2]; acc[dt][3] *= alpha[3];
      }
      bf16x8 pa = *(const bf16x8*)&sP[w][li * 32 + g8];
      #pragma unroll
      for (int dt = 0; dt < 8; ++dt) {
        bf16x8 vf = *(const bf16x8*)&sVt[(dt * 16 + li) * 32 + g8];
        acc[dt] = mfma16(pa, vf, acc[dt]);
      }
    }
    __syncthreads();
  }

  #pragma unroll
  for (int j = 0; j < 4; ++j) {
    float invl = 1.0f / l_[j];
    size_t base = (size_t)(qw0 + g * 4 + j) * HIDDEN + h * HD;
    #pragma unroll
    for (int dt = 0; dt < 8; ++dt)
      O[base + dt * 16 + li] = (bf16)(acc[dt][j] * invl);
  }
}

// ---------------- launcher --------------------------------------------------
extern "C" void kernel_launch(void* const* d_in, const int* in_sizes, int n_in,
                              void* d_out, int out_size, void* d_ws, size_t ws_size,
                              hipStream_t stream) {
  const float* X  = (const float*)d_in[0];
  const float* qw = (const float*)d_in[1];
  const float* kw = (const float*)d_in[2];
  const float* vw = (const float*)d_in[3];
  const float* ow = (const float*)d_in[4];
  const int* pos = (const int*)d_in[5];
  const int* cu  = (const int*)d_in[6];
  int T = in_sizes[0] / HIDDEN;     // 8192
  int B = in_sizes[6] - 1;          // 4
  float* out = (float*)d_out;

  // workspace layout (bf16 elements), total ~100 MB
  bf16* ws = (bf16*)d_ws;
  size_t off = 0;
  bf16* Xb   = ws + off; off += (size_t)T * HIDDEN;        // T x 2048 bf16 input
  bf16* Qb   = ws + off; off += (size_t)T * HIDDEN;        // T x 2048 (Q, then attn out)
  bf16* Kb   = ws + off; off += (size_t)T * (NKV * HD);    // T x 512
  bf16* Vt   = ws + off; off += (size_t)T * (NKV * HD);    // 512 x T (transposed)
  bf16* qwT  = ws + off; off += (size_t)HIDDEN * HIDDEN;
  bf16* kwT  = ws + off; off += (size_t)HIDDEN * (NKV * HD);
  bf16* vwT  = ws + off; off += (size_t)HIDDEN * (NKV * HD);
  bf16* owT  = ws + off; off += (size_t)HIDDEN * HIDDEN;

  cast_f32_bf16<<<(T * HIDDEN / 4 + 255) / 256, 256, 0, stream>>>(X, Xb, T * HIDDEN / 4);

  dim3 tb(32, 8);
  transpose_cast<<<dim3(HIDDEN / 32, HIDDEN / 32), tb, 0, stream>>>(qw, qwT, HIDDEN, HIDDEN);
  transpose_cast<<<dim3((NKV * HD) / 32, HIDDEN / 32), tb, 0, stream>>>(kw, kwT, HIDDEN, NKV * HD);
  transpose_cast<<<dim3((NKV * HD) / 32, HIDDEN / 32), tb, 0, stream>>>(vw, vwT, HIDDEN, NKV * HD);
  transpose_cast<<<dim3(HIDDEN / 32, HIDDEN / 32), tb, 0, stream>>>(ow, owT, HIDDEN, HIDDEN);

  gemm_bt<<<(T / 128) * (HIDDEN / 128), 256, 0, stream>>>(Xb, qwT, Qb, T, HIDDEN, HIDDEN, 0);
  gemm_bt<<<(T / 128) * ((NKV * HD) / 128), 256, 0, stream>>>(Xb, kwT, Kb, T, NKV * HD, HIDDEN, 0);
  gemm_bt<<<(T / 128) * ((NKV * HD) / 128), 256, 0, stream>>>(Xb, vwT, Vt, T, NKV * HD, HIDDEN, 1);

  rope_kernel<<<(T * NHEADS * 64 + 255) / 256, 256, 0, stream>>>(Qb, pos, T, NHEADS);
  rope_kernel<<<(T * NKV * 64 + 255) / 256, 256, 0, stream>>>(Kb, pos, T, NKV);

  // attention output aliases Qb (safe: per-block read-then-write of same region)
  attn_kernel<<<(T / 64) * NHEADS, 256, 0, stream>>>(Qb, Kb, Vt, pos, cu, Qb, T, B);

  gemm_bt<<<(T / 128) * (HIDDEN / 128), 256, 0, stream>>>(Qb, owT, out, T, HIDDEN, HIDDEN, 2);
}

// Round 3
// 449.249 us; speedup vs baseline: 1.1776x; 1.1776x over previous
//
#include <hip/hip_runtime.h>
#include <hip/hip_bf16.h>
#include <cstdint>
#include <cstddef>

typedef __bf16 bf16;
typedef __bf16 bf16x2 __attribute__((ext_vector_type(2)));
typedef __bf16 bf16x8 __attribute__((ext_vector_type(8)));
typedef float  f32x4  __attribute__((ext_vector_type(4)));

#define HIDDEN 2048
#define NHEADS 16
#define NKV    4
#define HD     128
#define WINDOW 512

// async global->LDS, 16B per lane; LDS dest is wave-uniform base + lane*16
__device__ __forceinline__ void gld16(const void* g, void* s) {
  __builtin_amdgcn_global_load_lds((const __attribute__((address_space(1))) void*)g,
                                   (__attribute__((address_space(3))) void*)s, 16, 0, 0);
}

__device__ __forceinline__ f32x4 mfma16(bf16x8 a, bf16x8 b, f32x4 c) {
  return __builtin_amdgcn_mfma_f32_16x16x32_bf16(a, b, c, 0, 0, 0);
}

// ---------------- cast fp32 -> bf16, 4 elems/thread -------------------------
__global__ __launch_bounds__(256) void cast_f32_bf16(const float* __restrict__ in,
                                                     bf16* __restrict__ out, int n4) {
  int i = blockIdx.x * 256 + threadIdx.x;
  if (i >= n4) return;
  f32x4 v = *(const f32x4*)(in + (size_t)i * 4);
  bf16x2 a, b;
  a[0] = (bf16)v[0]; a[1] = (bf16)v[1];
  b[0] = (bf16)v[2]; b[1] = (bf16)v[3];
  *(bf16x2*)(out + (size_t)i * 4)     = a;
  *(bf16x2*)(out + (size_t)i * 4 + 2) = b;
}

// ---------------- transpose+cast: fp32 (R x C) -> bf16 (C x R) --------------
__global__ __launch_bounds__(256) void transpose_cast(const float* __restrict__ in,
                                                      bf16* __restrict__ out, int R, int C) {
  __shared__ float tile[32][33];
  int c0 = blockIdx.x * 32, r0 = blockIdx.y * 32;
  int tx = threadIdx.x, ty = threadIdx.y;
  #pragma unroll
  for (int i = 0; i < 4; ++i)
    tile[ty + i * 8][tx] = in[(size_t)(r0 + ty + i * 8) * C + c0 + tx];
  __syncthreads();
  #pragma unroll
  for (int i = 0; i < 4; ++i)
    out[(size_t)(c0 + ty + i * 8) * R + r0 + tx] = (bf16)tile[tx][ty + i * 8];
}

// ---------------- GEMM: C(MxN) = A(MxK) * Bt(NxK)^T, bf16 in, f32 acc -------
// outMode: 0 = bf16 row-major, 1 = bf16 transposed (C^T), 2 = fp32 row-major
__device__ __forceinline__ void stage128x32(const bf16* __restrict__ A,
                                            const bf16* __restrict__ Bt,
                                            bf16* sA, bf16* sB,
                                            int m0, int n0, int K, int kt, int tid) {
  int wbase = tid & ~63;
  #pragma unroll
  for (int r = 0; r < 2; ++r) {
    int e = (r * 256 + tid) * 8;
    int row = e >> 5, col = e & 31;
    gld16(A  + (size_t)(m0 + row) * K + (size_t)kt * 32 + col,
          sA + (size_t)(r * 256 + wbase) * 8);
    gld16(Bt + (size_t)(n0 + row) * K + (size_t)kt * 32 + col,
          sB + (size_t)(r * 256 + wbase) * 8);
  }
}

__global__ __launch_bounds__(256) void gemm_bt(const bf16* __restrict__ A,
                                               const bf16* __restrict__ Bt,
                                               void* __restrict__ Cv,
                                               int M, int N, int K, int outMode) {
  __shared__ bf16 sA[2][128 * 32];
  __shared__ bf16 sB[2][128 * 32];
  int nb = N >> 7;
  int bm = (int)blockIdx.x / nb, bn = (int)blockIdx.x % nb;
  int m0 = bm << 7, n0 = bn << 7;
  int tid = threadIdx.x;
  int lane = tid & 63, w = tid >> 6;
  int li = lane & 15, g = lane >> 4, g8 = g * 8;
  int wm = w >> 1, wn = w & 1;
  f32x4 acc[4][4] = {};
  int NT = K >> 5;

  stage128x32(A, Bt, sA[0], sB[0], m0, n0, K, 0, tid);
  __syncthreads();
  for (int kt = 0; kt < NT; ++kt) {
    int cur = kt & 1;
    if (kt + 1 < NT)
      stage128x32(A, Bt, sA[cur ^ 1], sB[cur ^ 1], m0, n0, K, kt + 1, tid);
    bf16x8 af[4], bv[4];
    #pragma unroll
    for (int mt = 0; mt < 4; ++mt)
      af[mt] = *(const bf16x8*)&sA[cur][(wm * 64 + mt * 16 + li) * 32 + g8];
    #pragma unroll
    for (int nt = 0; nt < 4; ++nt)
      bv[nt] = *(const bf16x8*)&sB[cur][(wn * 64 + nt * 16 + li) * 32 + g8];
    #pragma unroll
    for (int mt = 0; mt < 4; ++mt)
      #pragma unroll
      for (int nt = 0; nt < 4; ++nt)
        acc[mt][nt] = mfma16(af[mt], bv[nt], acc[mt][nt]);
    __syncthreads();
  }
  // C/D layout: col = lane&15, row = (lane>>4)*4 + j   [m89/m91 verified]
  #pragma unroll
  for (int mt = 0; mt < 4; ++mt)
    #pragma unroll
    for (int nt = 0; nt < 4; ++nt)
      #pragma unroll
      for (int j = 0; j < 4; ++j) {
        int row = m0 + wm * 64 + mt * 16 + g * 4 + j;
        int col = n0 + wn * 64 + nt * 16 + li;
        float v = acc[mt][nt][j];
        if (outMode == 0)      ((bf16*)Cv)[(size_t)row * N + col] = (bf16)v;
        else if (outMode == 1) ((bf16*)Cv)[(size_t)col * M + row] = (bf16)v;  // C^T (Vt)
        else                   ((float*)Cv)[(size_t)row * N + col] = v;
      }
}

// ---------------- RoPE in place: X (T x heads*128), interleaved pairs -------
__global__ __launch_bounds__(256) void rope_kernel(bf16* __restrict__ X,
                                                   const int* __restrict__ pos,
                                                   int T, int heads) {
  int idx = blockIdx.x * 256 + threadIdx.x;
  int total = T * heads * 64;
  if (idx >= total) return;
  int i = idx & 63;
  int rest = idx >> 6;
  int hh = rest % heads;
  int t = rest / heads;
  float inv = expf((float)i * (-9.210340371976184f / 64.0f)); // theta^(-i/64)
  float ang = (float)pos[t] * inv;
  float s, c;
  sincosf(ang, &s, &c);
  bf16* p = X + ((size_t)t * heads + hh) * HD + 2 * i;
  bf16x2 xv = *(const bf16x2*)p;
  float xe = (float)xv[0], xo = (float)xv[1];
  bf16x2 r;
  r[0] = (bf16)(xe * c - xo * s);
  r[1] = (bf16)(xe * s + xo * c);
  *(bf16x2*)p = r;
}

// ---------------- sliding-window GQA flash attention ------------------------
// grid: (T/64)*16 blocks; 4 waves/block, each wave owns 16 q rows.
// No running max: scores are bounded (|s| <= |q||k|/sqrt(128) ~ 14), so
// p = exp(s*scale) is fp32/bf16-safe; l-sum deferred to epilogue (per-lane).
// LDS is conflict-free via chunk-XOR swizzles matched between the
// global_load_lds SOURCE address and the ds_read address (rule #21).
__global__ __launch_bounds__(256) void attn_kernel(const bf16* __restrict__ Q,
                                                   const bf16* __restrict__ Kb,
                                                   const bf16* __restrict__ Vt,
                                                   const int* __restrict__ pos,
                                                   const int* __restrict__ cu,
                                                   bf16* __restrict__ O, int T, int B) {
  __shared__ bf16 sK[32 * 128];    // data(row,chunk) stored at chunk^(row&7); 16B chunks
  __shared__ bf16 sVt2[64 * 64];   // LDS row r: d=2r (chunks 0-3), d=2r+1 (chunks 4-7), ^(r&7)
  __shared__ bf16 sP[4][16 * 40];  // per-wave P tile, stride 40 elems (80B) = conflict-free
  int bid = blockIdx.x;
  int h  = bid & (NHEADS - 1);
  int qb = bid >> 4;
  int q0 = qb * 64;
  int kvh = h >> 2;  // 16 heads -> 4 kv heads
  int tid = threadIdx.x, lane = tid & 63, w = tid >> 6;
  int li = lane & 15, g = lane >> 4, g8 = g * 8;
  int qw0 = q0 + w * 16;

  int seq_start = 0, seq_end = T;
  for (int b = 0; b < B; ++b) {
    int a = cu[b], e = cu[b + 1];
    if (q0 >= a && q0 < e) { seq_start = a; seq_end = e; }
  }

  // Q fragments: A-layout row=lane&15, k=(lane>>4)*8+j
  bf16x8 qf[4];
  #pragma unroll
  for (int kd = 0; kd < 4; ++kd)
    qf[kd] = *(const bf16x8*)(Q + (size_t)(qw0 + li) * HIDDEN + h * HD + kd * 32 + g8);

  int pq[4];
  #pragma unroll
  for (int j = 0; j < 4; ++j) pq[j] = pos[qw0 + g * 4 + j];
  int pqw_min = pos[qw0], pqw_max = pos[qw0 + 15];

  float lsum[4] = {0.f, 0.f, 0.f, 0.f};
  f32x4 acc[8] = {};

  int kstart = q0 - WINDOW;
  if (kstart < seq_start) kstart = seq_start;
  int kend = q0 + 64;
  if (kend > seq_end) kend = seq_end;
  const float scale = 0.08838834764831845f;  // 1/sqrt(128)

  for (int kb = kstart; kb < kend; kb += 32) {
    int wbase = tid & ~63;
    #pragma unroll
    for (int r = 0; r < 2; ++r) {
      int n = r * 256 + tid;
      // K tile: 32 rows x 128 el; source chunk = ldschunk ^ (row&7)
      int krow = n >> 4, kc = (n & 15) ^ (krow & 7);
      gld16(Kb + (size_t)(kb + krow) * (NKV * HD) + kvh * HD + kc * 8,
            sK + (size_t)(r * 256 + wbase) * 8);
      // V tile: LDS row vr holds d=2vr|2vr+1; source chunk = ldschunk ^ (vr&7)
      int vr = n >> 3, vc = (n & 7) ^ (vr & 7);
      int vd = 2 * vr + (vc >> 2), vkey = (vc & 3) * 8;
      gld16(Vt + (size_t)(kvh * HD + vd) * T + kb + vkey,
            sVt2 + (size_t)(r * 256 + wbase) * 8);
    }
    __syncthreads();

    int pkf = pos[kb], pkl = pos[kb + 31];
    bool active = !(pkf > pqw_max || pkl < pqw_min - WINDOW);
    if (active) {
      f32x4 s0v = {0.f, 0.f, 0.f, 0.f}, s1v = {0.f, 0.f, 0.f, 0.f};
      #pragma unroll
      for (int kd = 0; kd < 4; ++kd) {
        int chunk = kd * 4 + g;
        int c0 = chunk ^ (li & 7);           // same for row li and row 16+li
        bf16x8 b0 = *(const bf16x8*)&sK[li * 128 + c0 * 8];
        bf16x8 b1 = *(const bf16x8*)&sK[(16 + li) * 128 + c0 * 8];
        s0v = mfma16(qf[kd], b0, s0v);
        s1v = mfma16(qf[kd], b1, s1v);
      }
      int pk0 = pos[kb + li], pk1 = pos[kb + 16 + li];
      #pragma unroll
      for (int j = 0; j < 4; ++j) {
        int d0 = pq[j] - pk0, d1 = pq[j] - pk1;
        float p0 = (d0 >= 0 && d0 <= WINDOW) ? __expf(s0v[j] * scale) : 0.f;
        float p1 = (d1 >= 0 && d1 <= WINDOW) ? __expf(s1v[j] * scale) : 0.f;
        lsum[j] += p0 + p1;
        sP[w][(g * 4 + j) * 40 + li]      = (bf16)p0;
        sP[w][(g * 4 + j) * 40 + 16 + li] = (bf16)p1;
      }
      bf16x8 pa = *(const bf16x8*)&sP[w][li * 40 + g8];
      #pragma unroll
      for (int dt = 0; dt < 8; ++dt) {
        int d = dt * 16 + li;
        int vr = d >> 1;
        int vc = ((d & 1) * 4 + g) ^ (vr & 7);
        bf16x8 vf = *(const bf16x8*)&sVt2[vr * 64 + vc * 8];
        acc[dt] = mfma16(pa, vf, acc[dt]);
      }
    }
    __syncthreads();
  }

  #pragma unroll
  for (int j = 0; j < 4; ++j) {
    float rs = lsum[j];
    rs += __shfl_xor(rs, 1);
    rs += __shfl_xor(rs, 2);
    rs += __shfl_xor(rs, 4);
    rs += __shfl_xor(rs, 8);
    float invl = 1.0f / rs;
    size_t base = (size_t)(qw0 + g * 4 + j) * HIDDEN + h * HD;
    #pragma unroll
    for (int dt = 0; dt < 8; ++dt)
      O[base + dt * 16 + li] = (bf16)(acc[dt][j] * invl);
  }
}

// ---------------- launcher --------------------------------------------------
extern "C" void kernel_launch(void* const* d_in, const int* in_sizes, int n_in,
                              void* d_out, int out_size, void* d_ws, size_t ws_size,
                              hipStream_t stream) {
  const float* X  = (const float*)d_in[0];
  const float* qw = (const float*)d_in[1];
  const float* kw = (const float*)d_in[2];
  const float* vw = (const float*)d_in[3];
  const float* ow = (const float*)d_in[4];
  const int* pos = (const int*)d_in[5];
  const int* cu  = (const int*)d_in[6];
  int T = in_sizes[0] / HIDDEN;     // 8192
  int B = in_sizes[6] - 1;          // 4
  float* out = (float*)d_out;

  // workspace layout (bf16 elements), total ~100 MB
  bf16* ws = (bf16*)d_ws;
  size_t off = 0;
  bf16* Xb   = ws + off; off += (size_t)T * HIDDEN;        // T x 2048 bf16 input
  bf16* Qb   = ws + off; off += (size_t)T * HIDDEN;        // T x 2048 (Q, then attn out)
  bf16* Kb   = ws + off; off += (size_t)T * (NKV * HD);    // T x 512
  bf16* Vt   = ws + off; off += (size_t)T * (NKV * HD);    // 512 x T (transposed)
  bf16* qwT  = ws + off; off += (size_t)HIDDEN * HIDDEN;
  bf16* kwT  = ws + off; off += (size_t)HIDDEN * (NKV * HD);
  bf16* vwT  = ws + off; off += (size_t)HIDDEN * (NKV * HD);
  bf16* owT  = ws + off; off += (size_t)HIDDEN * HIDDEN;

  cast_f32_bf16<<<(T * HIDDEN / 4 + 255) / 256, 256, 0, stream>>>(X, Xb, T * HIDDEN / 4);

  dim3 tb(32, 8);
  transpose_cast<<<dim3(HIDDEN / 32, HIDDEN / 32), tb, 0, stream>>>(qw, qwT, HIDDEN, HIDDEN);
  transpose_cast<<<dim3((NKV * HD) / 32, HIDDEN / 32), tb, 0, stream>>>(kw, kwT, HIDDEN, NKV * HD);
  transpose_cast<<<dim3((NKV * HD) / 32, HIDDEN / 32), tb, 0, stream>>>(vw, vwT, HIDDEN, NKV * HD);
  transpose_cast<<<dim3(HIDDEN / 32, HIDDEN / 32), tb, 0, stream>>>(ow, owT, HIDDEN, HIDDEN);

  gemm_bt<<<(T / 128) * (HIDDEN / 128), 256, 0, stream>>>(Xb, qwT, Qb, T, HIDDEN, HIDDEN, 0);
  gemm_bt<<<(T / 128) * ((NKV * HD) / 128), 256, 0, stream>>>(Xb, kwT, Kb, T, NKV * HD, HIDDEN, 0);
  gemm_bt<<<(T / 128) * ((NKV * HD) / 128), 256, 0, stream>>>(Xb, vwT, Vt, T, NKV * HD, HIDDEN, 1);

  rope_kernel<<<(T * NHEADS * 64 + 255) / 256, 256, 0, stream>>>(Qb, pos, T, NHEADS);
  rope_kernel<<<(T * NKV * 64 + 255) / 256, 256, 0, stream>>>(Kb, pos, T, NKV);

  // attention output aliases Qb (safe: per-block read-then-write of same region)
  attn_kernel<<<(T / 64) * NHEADS, 256, 0, stream>>>(Qb, Kb, Vt, pos, cu, Qb, T, B);

  gemm_bt<<<(T / 128) * (HIDDEN / 128), 256, 0, stream>>>(Qb, owT, out, T, HIDDEN, HIDDEN, 2);
}

// Round 4
// 419.477 us; speedup vs baseline: 1.2611x; 1.0710x over previous
//
#include <hip/hip_runtime.h>
#include <hip/hip_bf16.h>
#include <cstdint>
#include <cstddef>

typedef __bf16 bf16;
typedef __bf16 bf16x2 __attribute__((ext_vector_type(2)));
typedef __bf16 bf16x8 __attribute__((ext_vector_type(8)));
typedef float  f32x4  __attribute__((ext_vector_type(4)));

#define HIDDEN 2048
#define NHEADS 16
#define NKV    4
#define HD     128
#define WINDOW 512

// async global->LDS, 16B per lane; LDS dest is wave-uniform base + lane*16
__device__ __forceinline__ void gld16(const void* g, void* s) {
  __builtin_amdgcn_global_load_lds((const __attribute__((address_space(1))) void*)g,
                                   (__attribute__((address_space(3))) void*)s, 16, 0, 0);
}

__device__ __forceinline__ f32x4 mfma16(bf16x8 a, bf16x8 b, f32x4 c) {
  return __builtin_amdgcn_mfma_f32_16x16x32_bf16(a, b, c, 0, 0, 0);
}

__device__ __forceinline__ void barrier_raw() {
  asm volatile("" ::: "memory");
  __builtin_amdgcn_s_barrier();
  asm volatile("" ::: "memory");
}

// ---------------- cast fp32 -> bf16, 4 elems/thread -------------------------
__global__ __launch_bounds__(256) void cast_f32_bf16(const float* __restrict__ in,
                                                     bf16* __restrict__ out, int n4) {
  int i = blockIdx.x * 256 + threadIdx.x;
  if (i >= n4) return;
  f32x4 v = *(const f32x4*)(in + (size_t)i * 4);
  bf16x2 a, b;
  a[0] = (bf16)v[0]; a[1] = (bf16)v[1];
  b[0] = (bf16)v[2]; b[1] = (bf16)v[3];
  *(bf16x2*)(out + (size_t)i * 4)     = a;
  *(bf16x2*)(out + (size_t)i * 4 + 2) = b;
}

// ---------------- transpose+cast: fp32 (R x C) -> bf16 (C x R) --------------
__global__ __launch_bounds__(256) void transpose_cast(const float* __restrict__ in,
                                                      bf16* __restrict__ out, int R, int C) {
  __shared__ float tile[32][33];
  int c0 = blockIdx.x * 32, r0 = blockIdx.y * 32;
  int tx = threadIdx.x, ty = threadIdx.y;
  #pragma unroll
  for (int i = 0; i < 4; ++i)
    tile[ty + i * 8][tx] = in[(size_t)(r0 + ty + i * 8) * C + c0 + tx];
  __syncthreads();
  #pragma unroll
  for (int i = 0; i < 4; ++i)
    out[(size_t)(c0 + ty + i * 8) * R + r0 + tx] = (bf16)tile[tx][ty + i * 8];
}

// ======================= 128x128 GEMM (K/V projections) =====================
__device__ __forceinline__ void stage128x32(const bf16* __restrict__ A,
                                            const bf16* __restrict__ Bt,
                                            bf16* sA, bf16* sB,
                                            int m0, int n0, int K, int kt, int tid) {
  int wbase = tid & ~63;
  #pragma unroll
  for (int r = 0; r < 2; ++r) {
    int e = (r * 256 + tid) * 8;
    int row = e >> 5, col = e & 31;
    gld16(A  + (size_t)(m0 + row) * K + (size_t)kt * 32 + col,
          sA + (size_t)(r * 256 + wbase) * 8);
    gld16(Bt + (size_t)(n0 + row) * K + (size_t)kt * 32 + col,
          sB + (size_t)(r * 256 + wbase) * 8);
  }
}

__global__ __launch_bounds__(256) void gemm_bt(const bf16* __restrict__ A,
                                               const bf16* __restrict__ Bt,
                                               void* __restrict__ Cv,
                                               int M, int N, int K, int outMode) {
  __shared__ bf16 sA[2][128 * 32];
  __shared__ bf16 sB[2][128 * 32];
  int nb = N >> 7;
  int bm = (int)blockIdx.x / nb, bn = (int)blockIdx.x % nb;
  int m0 = bm << 7, n0 = bn << 7;
  int tid = threadIdx.x;
  int lane = tid & 63, w = tid >> 6;
  int li = lane & 15, g = lane >> 4, g8 = g * 8;
  int wm = w >> 1, wn = w & 1;
  f32x4 acc[4][4] = {};
  int NT = K >> 5;

  stage128x32(A, Bt, sA[0], sB[0], m0, n0, K, 0, tid);
  __syncthreads();
  for (int kt = 0; kt < NT; ++kt) {
    int cur = kt & 1;
    if (kt + 1 < NT)
      stage128x32(A, Bt, sA[cur ^ 1], sB[cur ^ 1], m0, n0, K, kt + 1, tid);
    bf16x8 af[4], bv[4];
    #pragma unroll
    for (int mt = 0; mt < 4; ++mt)
      af[mt] = *(const bf16x8*)&sA[cur][(wm * 64 + mt * 16 + li) * 32 + g8];
    #pragma unroll
    for (int nt = 0; nt < 4; ++nt)
      bv[nt] = *(const bf16x8*)&sB[cur][(wn * 64 + nt * 16 + li) * 32 + g8];
    #pragma unroll
    for (int mt = 0; mt < 4; ++mt)
      #pragma unroll
      for (int nt = 0; nt < 4; ++nt)
        acc[mt][nt] = mfma16(af[mt], bv[nt], acc[mt][nt]);
    __syncthreads();
  }
  #pragma unroll
  for (int mt = 0; mt < 4; ++mt)
    #pragma unroll
    for (int nt = 0; nt < 4; ++nt)
      #pragma unroll
      for (int j = 0; j < 4; ++j) {
        int row = m0 + wm * 64 + mt * 16 + g * 4 + j;
        int col = n0 + wn * 64 + nt * 16 + li;
        float v = acc[mt][nt][j];
        if (outMode == 0)      ((bf16*)Cv)[(size_t)row * N + col] = (bf16)v;
        else if (outMode == 1) ((bf16*)Cv)[(size_t)col * M + row] = (bf16)v;  // C^T (Vt)
        else                   ((float*)Cv)[(size_t)row * N + col] = v;
      }
}

// ======================= 256x256 8-wave pipelined GEMM ======================
// BM=BN=256, BK=64, 512 threads (2x4 waves, each owns 128x64 of C).
// LDS: 2 dbuf x (A 256x64 + B 256x64) bf16 = 128 KiB, chunk-XOR swizzled
// (chunk ^= row&7, inverse-swizzle applied to the global SOURCE, rule #21).
// 4 phases/K-tile, zigzag quadrants; 1 half-tile staged per phase; counted
// s_waitcnt vmcnt(2) once per K-tile (never 0 in main loop); raw s_barrier.
__device__ __forceinline__ void stage_half256(const bf16* __restrict__ G,
                                              bf16* __restrict__ sbuf,
                                              int row0, int K, int k0, int h, int tid) {
  int w = tid >> 6, lane = tid & 63;
  #pragma unroll
  for (int r = 0; r < 2; ++r) {
    int hi = w * 128 + r * 64 + lane;                  // 0..1023 chunk id in half
    int row = (hi >> 3);                               // 0..127 row in half
    int col = ((hi & 7) ^ (row & 7)) * 8;              // inverse-swizzled source col
    gld16(G + (size_t)(row0 + h * 128 + row) * K + k0 + col,
          sbuf + h * 8192 + w * 1024 + r * 512);       // wave-uniform LDS base
  }
}

__global__ __launch_bounds__(512, 2) void gemm256(const bf16* __restrict__ A,
                                                  const bf16* __restrict__ Bt,
                                                  void* __restrict__ Cv,
                                                  int M, int N, int K, int outMode) {
  __shared__ bf16 sA[2][256 * 64];
  __shared__ bf16 sB[2][256 * 64];
  int nb = N >> 8;
  int bm = (int)blockIdx.x / nb, bn = (int)blockIdx.x % nb;
  int m0 = bm << 8, n0 = bn << 8;
  int tid = threadIdx.x, lane = tid & 63, w = tid >> 6;
  int li = lane & 15, g = lane >> 4;
  int wm = w >> 2, wn = w & 3;                         // 2 x 4 wave grid
  int swz = (li & 7);                                  // row&7 == li&7 for all frags

  f32x4 acc[8][4] = {};
  bf16x8 af[4][2];       // A frags for current mh: 4 m-frags x 2 k-slices
  bf16x8 bf[2][2][2];    // B frags, both nh halves: [nh][nf][ks]

  int NT = K >> 6;

  // prologue: stage K-tile 0 (4 half-tiles, 8 loads/thread)
  stage_half256(A,  sA[0], m0, K, 0, 0, tid);
  stage_half256(A,  sA[0], m0, K, 0, 1, tid);
  stage_half256(Bt, sB[0], n0, K, 0, 0, tid);
  stage_half256(Bt, sB[0], n0, K, 0, 1, tid);

#define LOAD_A256(mh) { _Pragma("unroll") for (int mf = 0; mf < 4; ++mf) \
  _Pragma("unroll") for (int ks = 0; ks < 2; ++ks) { \
    int row = wm * 128 + (mh) * 64 + mf * 16 + li; \
    af[mf][ks] = *(const bf16x8*)&sA[cur][row * 64 + ((ks * 4 + g) ^ swz) * 8]; } }
#define LOAD_B256(nh) { _Pragma("unroll") for (int nf = 0; nf < 2; ++nf) \
  _Pragma("unroll") for (int ks = 0; ks < 2; ++ks) { \
    int row = wn * 64 + (nh) * 32 + nf * 16 + li; \
    bf[nh][nf][ks] = *(const bf16x8*)&sB[cur][row * 64 + ((ks * 4 + g) ^ swz) * 8]; } }
#define MFMA_PH(mh, nh) { \
  asm volatile("s_waitcnt lgkmcnt(0)" ::: "memory"); \
  __builtin_amdgcn_sched_barrier(0); \
  __builtin_amdgcn_s_setprio(1); \
  _Pragma("unroll") for (int mf = 0; mf < 4; ++mf) \
  _Pragma("unroll") for (int nf = 0; nf < 2; ++nf) \
  _Pragma("unroll") for (int ks = 0; ks < 2; ++ks) \
    acc[(mh) * 4 + mf][(nh) * 2 + nf] = \
      mfma16(af[mf][ks], bf[nh][nf][ks], acc[(mh) * 4 + mf][(nh) * 2 + nf]); \
  __builtin_amdgcn_s_setprio(0); }

  int cur = 0;
  for (int t = 0; t < NT; ++t) {
    int nxt = cur ^ 1;
    bool pre = (t + 1 < NT);
    int k1 = (t + 1) << 6;
    // ---- phase 0: quadrant (mh0, nh0) ----
    if (pre) {
      stage_half256(A, sA[nxt], m0, K, k1, 0, tid);
      asm volatile("s_waitcnt vmcnt(2)" ::: "memory");   // tile-t resident, 2 in flight
    } else {
      asm volatile("s_waitcnt vmcnt(0)" ::: "memory");
    }
    barrier_raw();
    LOAD_A256(0); LOAD_B256(0);
    MFMA_PH(0, 0);
    barrier_raw();
    // ---- phase 1: quadrant (mh0, nh1) ----
    if (pre) stage_half256(A, sA[nxt], m0, K, k1, 1, tid);
    LOAD_B256(1);
    MFMA_PH(0, 1);
    barrier_raw();
    // ---- phase 2: quadrant (mh1, nh1) ----
    if (pre) stage_half256(Bt, sB[nxt], n0, K, k1, 0, tid);
    LOAD_A256(1);
    MFMA_PH(1, 1);
    barrier_raw();
    // ---- phase 3: quadrant (mh1, nh0) ----
    if (pre) stage_half256(Bt, sB[nxt], n0, K, k1, 1, tid);
    MFMA_PH(1, 0);
    barrier_raw();
    cur = nxt;
  }
#undef LOAD_A256
#undef LOAD_B256
#undef MFMA_PH

  #pragma unroll
  for (int mi = 0; mi < 8; ++mi)
    #pragma unroll
    for (int ni = 0; ni < 4; ++ni)
      #pragma unroll
      for (int j = 0; j < 4; ++j) {
        int row = m0 + wm * 128 + mi * 16 + g * 4 + j;
        int col = n0 + wn * 64 + ni * 16 + li;
        float v = acc[mi][ni][j];
        if (outMode == 0) ((bf16*)Cv)[(size_t)row * N + col] = (bf16)v;
        else              ((float*)Cv)[(size_t)row * N + col] = v;
      }
}

// ---------------- RoPE in place: X (T x heads*128), interleaved pairs -------
__global__ __launch_bounds__(256) void rope_kernel(bf16* __restrict__ X,
                                                   const int* __restrict__ pos,
                                                   int T, int heads) {
  int idx = blockIdx.x * 256 + threadIdx.x;
  int total = T * heads * 64;
  if (idx >= total) return;
  int i = idx & 63;
  int rest = idx >> 6;
  int hh = rest % heads;
  int t = rest / heads;
  float inv = expf((float)i * (-9.210340371976184f / 64.0f)); // theta^(-i/64)
  float ang = (float)pos[t] * inv;
  float s, c;
  sincosf(ang, &s, &c);
  bf16* p = X + ((size_t)t * heads + hh) * HD + 2 * i;
  bf16x2 xv = *(const bf16x2*)p;
  float xe = (float)xv[0], xo = (float)xv[1];
  bf16x2 r;
  r[0] = (bf16)(xe * c - xo * s);
  r[1] = (bf16)(xe * s + xo * c);
  *(bf16x2*)p = r;
}

// ---------------- sliding-window GQA flash attention ------------------------
__global__ __launch_bounds__(256) void attn_kernel(const bf16* __restrict__ Q,
                                                   const bf16* __restrict__ Kb,
                                                   const bf16* __restrict__ Vt,
                                                   const int* __restrict__ pos,
                                                   const int* __restrict__ cu,
                                                   bf16* __restrict__ O, int T, int B) {
  __shared__ bf16 sK[32 * 128];    // data(row,chunk) stored at chunk^(row&7); 16B chunks
  __shared__ bf16 sVt2[64 * 64];   // LDS row r: d=2r (chunks 0-3), d=2r+1 (chunks 4-7), ^(r&7)
  __shared__ bf16 sP[4][16 * 40];  // per-wave P tile, stride 40 elems (80B) = conflict-free
  int bid = blockIdx.x;
  int h  = bid & (NHEADS - 1);
  int qb = bid >> 4;
  int q0 = qb * 64;
  int kvh = h >> 2;  // 16 heads -> 4 kv heads
  int tid = threadIdx.x, lane = tid & 63, w = tid >> 6;
  int li = lane & 15, g = lane >> 4, g8 = g * 8;
  int qw0 = q0 + w * 16;

  int seq_start = 0, seq_end = T;
  for (int b = 0; b < B; ++b) {
    int a = cu[b], e = cu[b + 1];
    if (q0 >= a && q0 < e) { seq_start = a; seq_end = e; }
  }

  bf16x8 qf[4];
  #pragma unroll
  for (int kd = 0; kd < 4; ++kd)
    qf[kd] = *(const bf16x8*)(Q + (size_t)(qw0 + li) * HIDDEN + h * HD + kd * 32 + g8);

  int pq[4];
  #pragma unroll
  for (int j = 0; j < 4; ++j) pq[j] = pos[qw0 + g * 4 + j];
  int pqw_min = pos[qw0], pqw_max = pos[qw0 + 15];

  float lsum[4] = {0.f, 0.f, 0.f, 0.f};
  f32x4 acc[8] = {};

  int kstart = q0 - WINDOW;
  if (kstart < seq_start) kstart = seq_start;
  int kend = q0 + 64;
  if (kend > seq_end) kend = seq_end;
  const float scale = 0.08838834764831845f;  // 1/sqrt(128)

  for (int kb = kstart; kb < kend; kb += 32) {
    int wbase = tid & ~63;
    #pragma unroll
    for (int r = 0; r < 2; ++r) {
      int n = r * 256 + tid;
      int krow = n >> 4, kc = (n & 15) ^ (krow & 7);
      gld16(Kb + (size_t)(kb + krow) * (NKV * HD) + kvh * HD + kc * 8,
            sK + (size_t)(r * 256 + wbase) * 8);
      int vr = n >> 3, vc = (n & 7) ^ (vr & 7);
      int vd = 2 * vr + (vc >> 2), vkey = (vc & 3) * 8;
      gld16(Vt + (size_t)(kvh * HD + vd) * T + kb + vkey,
            sVt2 + (size_t)(r * 256 + wbase) * 8);
    }
    __syncthreads();

    int pkf = pos[kb], pkl = pos[kb + 31];
    bool active = !(pkf > pqw_max || pkl < pqw_min - WINDOW);
    if (active) {
      f32x4 s0v = {0.f, 0.f, 0.f, 0.f}, s1v = {0.f, 0.f, 0.f, 0.f};
      #pragma unroll
      for (int kd = 0; kd < 4; ++kd) {
        int chunk = kd * 4 + g;
        int c0 = chunk ^ (li & 7);
        bf16x8 b0 = *(const bf16x8*)&sK[li * 128 + c0 * 8];
        bf16x8 b1 = *(const bf16x8*)&sK[(16 + li) * 128 + c0 * 8];
        s0v = mfma16(qf[kd], b0, s0v);
        s1v = mfma16(qf[kd], b1, s1v);
      }
      int pk0 = pos[kb + li], pk1 = pos[kb + 16 + li];
      #pragma unroll
      for (int j = 0; j < 4; ++j) {
        int d0 = pq[j] - pk0, d1 = pq[j] - pk1;
        float p0 = (d0 >= 0 && d0 <= WINDOW) ? __expf(s0v[j] * scale) : 0.f;
        float p1 = (d1 >= 0 && d1 <= WINDOW) ? __expf(s1v[j] * scale) : 0.f;
        lsum[j] += p0 + p1;
        sP[w][(g * 4 + j) * 40 + li]      = (bf16)p0;
        sP[w][(g * 4 + j) * 40 + 16 + li] = (bf16)p1;
      }
      bf16x8 pa = *(const bf16x8*)&sP[w][li * 40 + g8];
      #pragma unroll
      for (int dt = 0; dt < 8; ++dt) {
        int d = dt * 16 + li;
        int vr = d >> 1;
        int vc = ((d & 1) * 4 + g) ^ (vr & 7);
        bf16x8 vf = *(const bf16x8*)&sVt2[vr * 64 + vc * 8];
        acc[dt] = mfma16(pa, vf, acc[dt]);
      }
    }
    __syncthreads();
  }

  #pragma unroll
  for (int j = 0; j < 4; ++j) {
    float rs = lsum[j];
    rs += __shfl_xor(rs, 1);
    rs += __shfl_xor(rs, 2);
    rs += __shfl_xor(rs, 4);
    rs += __shfl_xor(rs, 8);
    float invl = 1.0f / rs;
    size_t base = (size_t)(qw0 + g * 4 + j) * HIDDEN + h * HD;
    #pragma unroll
    for (int dt = 0; dt < 8; ++dt)
      O[base + dt * 16 + li] = (bf16)(acc[dt][j] * invl);
  }
}

// ---------------- launcher --------------------------------------------------
extern "C" void kernel_launch(void* const* d_in, const int* in_sizes, int n_in,
                              void* d_out, int out_size, void* d_ws, size_t ws_size,
                              hipStream_t stream) {
  const float* X  = (const float*)d_in[0];
  const float* qw = (const float*)d_in[1];
  const float* kw = (const float*)d_in[2];
  const float* vw = (const float*)d_in[3];
  const float* ow = (const float*)d_in[4];
  const int* pos = (const int*)d_in[5];
  const int* cu  = (const int*)d_in[6];
  int T = in_sizes[0] / HIDDEN;     // 8192
  int B = in_sizes[6] - 1;          // 4
  float* out = (float*)d_out;

  bf16* ws = (bf16*)d_ws;
  size_t off = 0;
  bf16* Xb   = ws + off; off += (size_t)T * HIDDEN;
  bf16* Qb   = ws + off; off += (size_t)T * HIDDEN;        // Q, then attn out
  bf16* Kb   = ws + off; off += (size_t)T * (NKV * HD);
  bf16* Vt   = ws + off; off += (size_t)T * (NKV * HD);
  bf16* qwT  = ws + off; off += (size_t)HIDDEN * HIDDEN;
  bf16* kwT  = ws + off; off += (size_t)HIDDEN * (NKV * HD);
  bf16* vwT  = ws + off; off += (size_t)HIDDEN * (NKV * HD);
  bf16* owT  = ws + off; off += (size_t)HIDDEN * HIDDEN;

  cast_f32_bf16<<<(T * HIDDEN / 4 + 255) / 256, 256, 0, stream>>>(X, Xb, T * HIDDEN / 4);

  dim3 tb(32, 8);
  transpose_cast<<<dim3(HIDDEN / 32, HIDDEN / 32), tb, 0, stream>>>(qw, qwT, HIDDEN, HIDDEN);
  transpose_cast<<<dim3((NKV * HD) / 32, HIDDEN / 32), tb, 0, stream>>>(kw, kwT, HIDDEN, NKV * HD);
  transpose_cast<<<dim3((NKV * HD) / 32, HIDDEN / 32), tb, 0, stream>>>(vw, vwT, HIDDEN, NKV * HD);
  transpose_cast<<<dim3(HIDDEN / 32, HIDDEN / 32), tb, 0, stream>>>(ow, owT, HIDDEN, HIDDEN);

  // Q-projection: 256x256 pipelined GEMM (bf16 out)
  gemm256<<<(T / 256) * (HIDDEN / 256), 512, 0, stream>>>(Xb, qwT, Qb, T, HIDDEN, HIDDEN, 0);
  // K/V projections: thin N -> 128x128 kernel keeps 256-block grids
  gemm_bt<<<(T / 128) * ((NKV * HD) / 128), 256, 0, stream>>>(Xb, kwT, Kb, T, NKV * HD, HIDDEN, 0);
  gemm_bt<<<(T / 128) * ((NKV * HD) / 128), 256, 0, stream>>>(Xb, vwT, Vt, T, NKV * HD, HIDDEN, 1);

  rope_kernel<<<(T * NHEADS * 64 + 255) / 256, 256, 0, stream>>>(Qb, pos, T, NHEADS);
  rope_kernel<<<(T * NKV * 64 + 255) / 256, 256, 0, stream>>>(Kb, pos, T, NKV);

  attn_kernel<<<(T / 64) * NHEADS, 256, 0, stream>>>(Qb, Kb, Vt, pos, cu, Qb, T, B);

  // O-projection: 256x256 pipelined GEMM (fp32 out)
  gemm256<<<(T / 256) * (HIDDEN / 256), 512, 0, stream>>>(Qb, owT, out, T, HIDDEN, HIDDEN, 2);
}

// Round 5
// 380.575 us; speedup vs baseline: 1.3900x; 1.1022x over previous
//
#include <hip/hip_runtime.h>
#include <hip/hip_bf16.h>
#include <cstdint>
#include <cstddef>

typedef __bf16 bf16;
typedef __bf16 bf16x2 __attribute__((ext_vector_type(2)));
typedef __bf16 bf16x8 __attribute__((ext_vector_type(8)));
typedef float  f32x4  __attribute__((ext_vector_type(4)));

#define HIDDEN 2048
#define NHEADS 16
#define NKV    4
#define HD     128
#define WINDOW 512

// async global->LDS, 16B per lane; LDS dest is wave-uniform base + lane*16
__device__ __forceinline__ void gld16(const void* g, void* s) {
  __builtin_amdgcn_global_load_lds((const __attribute__((address_space(1))) void*)g,
                                   (__attribute__((address_space(3))) void*)s, 16, 0, 0);
}

__device__ __forceinline__ f32x4 mfma16(bf16x8 a, bf16x8 b, f32x4 c) {
  return __builtin_amdgcn_mfma_f32_16x16x32_bf16(a, b, c, 0, 0, 0);
}

__device__ __forceinline__ void barrier_raw() {
  asm volatile("" ::: "memory");
  __builtin_amdgcn_s_barrier();
  asm volatile("" ::: "memory");
}

// ---------------- cast fp32 -> bf16, 4 elems/thread -------------------------
__global__ __launch_bounds__(256) void cast_f32_bf16(const float* __restrict__ in,
                                                     bf16* __restrict__ out, int n4) {
  int i = blockIdx.x * 256 + threadIdx.x;
  if (i >= n4) return;
  f32x4 v = *(const f32x4*)(in + (size_t)i * 4);
  bf16x2 a, b;
  a[0] = (bf16)v[0]; a[1] = (bf16)v[1];
  b[0] = (bf16)v[2]; b[1] = (bf16)v[3];
  *(bf16x2*)(out + (size_t)i * 4)     = a;
  *(bf16x2*)(out + (size_t)i * 4 + 2) = b;
}

// ---------------- transpose+cast: fp32 (R x C) -> bf16 (C x R) --------------
__global__ __launch_bounds__(256) void transpose_cast(const float* __restrict__ in,
                                                      bf16* __restrict__ out, int R, int C) {
  __shared__ float tile[32][33];
  int c0 = blockIdx.x * 32, r0 = blockIdx.y * 32;
  int tx = threadIdx.x, ty = threadIdx.y;
  #pragma unroll
  for (int i = 0; i < 4; ++i)
    tile[ty + i * 8][tx] = in[(size_t)(r0 + ty + i * 8) * C + c0 + tx];
  __syncthreads();
  #pragma unroll
  for (int i = 0; i < 4; ++i)
    out[(size_t)(c0 + ty + i * 8) * R + r0 + tx] = (bf16)tile[tx][ty + i * 8];
}

// ======================= 256x256 8-wave pipelined GEMM ======================
// BM=BN=256, BK=64, 512 threads (2x4 waves, each owns 128x64 of C).
// Quadrant-aligned staging: each stage covers exactly one quadrant operand's
// row set (A-half mh = rows with bit6==mh; B-half nh = rows with bit5==nh).
// Issue order per K-tile: A0, B0, B1, A1 (one per phase). Counted vmcnt(6)
// keeps 3 half-tiles in flight -> every awaited load is >=3 phases old.
// One barrier per phase; phase 3 needs none (its operands were waited/
// barriered at phases 0/2, and next-iter stages touch disjoint LDS regions).
template<int RSP>  // 64 for A halves, 32 for B halves
__device__ __forceinline__ void stage_quad(const bf16* __restrict__ G,
                                           bf16* __restrict__ sbuf,
                                           int grow0, int K, int k0, int half, int tid) {
  int w = tid >> 6, lane = tid & 63;
  int rl = lane >> 3;                         // row within the 8-row group
  int col = ((lane & 7) ^ rl) * 8;            // inverse-swizzled SOURCE col (rule #21)
  #pragma unroll
  for (int r = 0; r < 2; ++r) {
    int lr0 = r * 64 + w * 8;                 // multiple of 8, 0..120
    int row0 = (lr0 & (RSP - 1)) + half * RSP + (lr0 / RSP) * 2 * RSP;
    gld16(G + (size_t)(grow0 + row0 + rl) * K + k0 + col,
          sbuf + row0 * 64);                  // wave-uniform linear LDS dest
  }
}

// outMode: 0 = bf16 row-major; 2 = fp32 row-major; 3 = fused QKV split
__global__ __launch_bounds__(512, 2) void gemm256(const bf16* __restrict__ A,
                                                  const bf16* __restrict__ Bt,
                                                  void* __restrict__ Cv,
                                                  bf16* __restrict__ Kout,
                                                  bf16* __restrict__ Vtout,
                                                  int M, int N, int K, int outMode) {
  __shared__ bf16 sA[2][256 * 64];
  __shared__ bf16 sB[2][256 * 64];
  int nb = N >> 8;
  // XCD-aware bijective swizzle (grid is a multiple of 8)
  int cpx = (int)gridDim.x >> 3;
  int bid = (int)blockIdx.x;
  int swzb = (bid & 7) * cpx + (bid >> 3);
  int bm = swzb / nb, bn = swzb % nb;
  int m0 = bm << 8, n0 = bn << 8;
  int tid = threadIdx.x, lane = tid & 63, w = tid >> 6;
  int li = lane & 15, g = lane >> 4;
  int wm = w >> 2, wn = w & 3;                // 2 x 4 wave grid
  int swz = (li & 7);

  f32x4 acc[8][4] = {};
  bf16x8 af[4][2];       // A frags for current mh
  bf16x8 bv[2][2][2];    // B frags, both nh halves: [nh][nf][ks]

  int NT = K >> 6;

  // prologue: tile 0 in consumption order A0, B0, B1, A1
  stage_quad<64>(A,  sA[0], m0, K, 0, 0, tid);
  stage_quad<32>(Bt, sB[0], n0, K, 0, 0, tid);
  stage_quad<32>(Bt, sB[0], n0, K, 0, 1, tid);
  stage_quad<64>(A,  sA[0], m0, K, 0, 1, tid);

#define VMW(n) asm volatile("s_waitcnt vmcnt(" #n ")" ::: "memory")
#define LOAD_A256(mh) { _Pragma("unroll") for (int mf = 0; mf < 4; ++mf) \
  _Pragma("unroll") for (int ks = 0; ks < 2; ++ks) { \
    int row = wm * 128 + (mh) * 64 + mf * 16 + li; \
    af[mf][ks] = *(const bf16x8*)&sA[cur][row * 64 + ((ks * 4 + g) ^ swz) * 8]; } }
#define LOAD_B256(nh) { _Pragma("unroll") for (int nf = 0; nf < 2; ++nf) \
  _Pragma("unroll") for (int ks = 0; ks < 2; ++ks) { \
    int row = wn * 64 + (nh) * 32 + nf * 16 + li; \
    bv[nh][nf][ks] = *(const bf16x8*)&sB[cur][row * 64 + ((ks * 4 + g) ^ swz) * 8]; } }
#define LGKM0() { asm volatile("s_waitcnt lgkmcnt(0)" ::: "memory"); \
  __builtin_amdgcn_sched_barrier(0); }
#define MFMA_PH(mh, nh) { \
  __builtin_amdgcn_s_setprio(1); \
  _Pragma("unroll") for (int mf = 0; mf < 4; ++mf) \
  _Pragma("unroll") for (int nf = 0; nf < 2; ++nf) \
  _Pragma("unroll") for (int ks = 0; ks < 2; ++ks) \
    acc[(mh) * 4 + mf][(nh) * 2 + nf] = \
      mfma16(af[mf][ks], bv[nh][nf][ks], acc[(mh) * 4 + mf][(nh) * 2 + nf]); \
  __builtin_amdgcn_s_setprio(0); }

  int cur = 0;
  for (int t = 0; t < NT; ++t) {
    int nxt = cur ^ 1;
    bool pre = (t + 1 < NT);
    int k1 = (t + 1) << 6;
    // ---- phase 0: quadrant (mh0, nh0); needs A0,B0 (issued >=3 phases ago)
    if (pre) { stage_quad<64>(A, sA[nxt], m0, K, k1, 0, tid); VMW(6); }
    else     { VMW(4); }
    barrier_raw();
    LOAD_A256(0); LOAD_B256(0);
    LGKM0();
    MFMA_PH(0, 0);
    // ---- phase 1: quadrant (mh0, nh1); needs B1
    if (pre) { stage_quad<32>(Bt, sB[nxt], n0, K, k1, 0, tid); VMW(6); }
    else     { VMW(2); }
    barrier_raw();
    LOAD_B256(1);
    LGKM0();
    MFMA_PH(0, 1);
    // ---- phase 2: quadrant (mh1, nh1); needs A1
    if (pre) { stage_quad<32>(Bt, sB[nxt], n0, K, k1, 1, tid); VMW(6); }
    else     { VMW(0); }
    barrier_raw();
    LOAD_A256(1);
    LGKM0();
    MFMA_PH(1, 1);
    // ---- phase 3: quadrant (mh1, nh0); operands already in registers
    if (pre) stage_quad<64>(A, sA[nxt], m0, K, k1, 1, tid);
    MFMA_PH(1, 0);
    cur = nxt;
  }
#undef VMW
#undef LOAD_A256
#undef LOAD_B256
#undef LGKM0
#undef MFMA_PH

  #pragma unroll
  for (int mi = 0; mi < 8; ++mi)
    #pragma unroll
    for (int ni = 0; ni < 4; ++ni)
      #pragma unroll
      for (int j = 0; j < 4; ++j) {
        int row = m0 + wm * 128 + mi * 16 + g * 4 + j;
        int col = n0 + wn * 64 + ni * 16 + li;
        float v = acc[mi][ni][j];
        if (outMode == 2) {
          ((float*)Cv)[(size_t)row * N + col] = v;
        } else if (outMode == 0) {
          ((bf16*)Cv)[(size_t)row * N + col] = (bf16)v;
        } else {  // 3: fused QKV (N==3072): Q | K | V^T
          if (col < 2048)      ((bf16*)Cv)[(size_t)row * 2048 + col] = (bf16)v;
          else if (col < 2560) Kout[(size_t)row * 512 + (col - 2048)] = (bf16)v;
          else                 Vtout[(size_t)(col - 2560) * M + row] = (bf16)v;
        }
      }
}

// ---------------- RoPE in place: X (T x heads*128), interleaved pairs -------
__global__ __launch_bounds__(256) void rope_kernel(bf16* __restrict__ X,
                                                   const int* __restrict__ pos,
                                                   int T, int heads) {
  int idx = blockIdx.x * 256 + threadIdx.x;
  int total = T * heads * 64;
  if (idx >= total) return;
  int i = idx & 63;
  int rest = idx >> 6;
  int hh = rest % heads;
  int t = rest / heads;
  float inv = expf((float)i * (-9.210340371976184f / 64.0f)); // theta^(-i/64)
  float ang = (float)pos[t] * inv;
  float s, c;
  sincosf(ang, &s, &c);
  bf16* p = X + ((size_t)t * heads + hh) * HD + 2 * i;
  bf16x2 xv = *(const bf16x2*)p;
  float xe = (float)xv[0], xo = (float)xv[1];
  bf16x2 r;
  r[0] = (bf16)(xe * c - xo * s);
  r[1] = (bf16)(xe * s + xo * c);
  *(bf16x2*)p = r;
}

// ---------------- sliding-window GQA flash attention ------------------------
__global__ __launch_bounds__(256) void attn_kernel(const bf16* __restrict__ Q,
                                                   const bf16* __restrict__ Kb,
                                                   const bf16* __restrict__ Vt,
                                                   const int* __restrict__ pos,
                                                   const int* __restrict__ cu,
                                                   bf16* __restrict__ O, int T, int B) {
  __shared__ bf16 sK[32 * 128];    // data(row,chunk) stored at chunk^(row&7); 16B chunks
  __shared__ bf16 sVt2[64 * 64];   // LDS row r: d=2r (chunks 0-3), d=2r+1 (chunks 4-7), ^(r&7)
  __shared__ bf16 sP[4][16 * 40];  // per-wave P tile, stride 40 elems = conflict-free
  int bid = blockIdx.x;
  int h  = bid & (NHEADS - 1);
  int qb = bid >> 4;
  int q0 = qb * 64;
  int kvh = h >> 2;
  int tid = threadIdx.x, lane = tid & 63, w = tid >> 6;
  int li = lane & 15, g = lane >> 4, g8 = g * 8;
  int qw0 = q0 + w * 16;

  int seq_start = 0, seq_end = T;
  for (int b = 0; b < B; ++b) {
    int a = cu[b], e = cu[b + 1];
    if (q0 >= a && q0 < e) { seq_start = a; seq_end = e; }
  }

  bf16x8 qf[4];
  #pragma unroll
  for (int kd = 0; kd < 4; ++kd)
    qf[kd] = *(const bf16x8*)(Q + (size_t)(qw0 + li) * HIDDEN + h * HD + kd * 32 + g8);

  int pq[4];
  #pragma unroll
  for (int j = 0; j < 4; ++j) pq[j] = pos[qw0 + g * 4 + j];
  int pqw_min = pos[qw0], pqw_max = pos[qw0 + 15];

  float lsum[4] = {0.f, 0.f, 0.f, 0.f};
  f32x4 acc[8] = {};

  int kstart = q0 - WINDOW;
  if (kstart < seq_start) kstart = seq_start;
  int kend = q0 + 64;
  if (kend > seq_end) kend = seq_end;
  const float scale = 0.08838834764831845f;

  for (int kb = kstart; kb < kend; kb += 32) {
    int wbase = tid & ~63;
    #pragma unroll
    for (int r = 0; r < 2; ++r) {
      int n = r * 256 + tid;
      int krow = n >> 4, kc = (n & 15) ^ (krow & 7);
      gld16(Kb + (size_t)(kb + krow) * (NKV * HD) + kvh * HD + kc * 8,
            sK + (size_t)(r * 256 + wbase) * 8);
      int vr = n >> 3, vc = (n & 7) ^ (vr & 7);
      int vd = 2 * vr + (vc >> 2), vkey = (vc & 3) * 8;
      gld16(Vt + (size_t)(kvh * HD + vd) * T + kb + vkey,
            sVt2 + (size_t)(r * 256 + wbase) * 8);
    }
    __syncthreads();

    int pkf = pos[kb], pkl = pos[kb + 31];
    bool active = !(pkf > pqw_max || pkl < pqw_min - WINDOW);
    if (active) {
      f32x4 s0v = {0.f, 0.f, 0.f, 0.f}, s1v = {0.f, 0.f, 0.f, 0.f};
      #pragma unroll
      for (int kd = 0; kd < 4; ++kd) {
        int chunk = kd * 4 + g;
        int c0 = chunk ^ (li & 7);
        bf16x8 b0 = *(const bf16x8*)&sK[li * 128 + c0 * 8];
        bf16x8 b1 = *(const bf16x8*)&sK[(16 + li) * 128 + c0 * 8];
        s0v = mfma16(qf[kd], b0, s0v);
        s1v = mfma16(qf[kd], b1, s1v);
      }
      int pk0 = pos[kb + li], pk1 = pos[kb + 16 + li];
      #pragma unroll
      for (int j = 0; j < 4; ++j) {
        int d0 = pq[j] - pk0, d1 = pq[j] - pk1;
        float p0 = (d0 >= 0 && d0 <= WINDOW) ? __expf(s0v[j] * scale) : 0.f;
        float p1 = (d1 >= 0 && d1 <= WINDOW) ? __expf(s1v[j] * scale) : 0.f;
        lsum[j] += p0 + p1;
        sP[w][(g * 4 + j) * 40 + li]      = (bf16)p0;
        sP[w][(g * 4 + j) * 40 + 16 + li] = (bf16)p1;
      }
      bf16x8 pa = *(const bf16x8*)&sP[w][li * 40 + g8];
      #pragma unroll
      for (int dt = 0; dt < 8; ++dt) {
        int d = dt * 16 + li;
        int vr = d >> 1;
        int vc = ((d & 1) * 4 + g) ^ (vr & 7);
        bf16x8 vf = *(const bf16x8*)&sVt2[vr * 64 + vc * 8];
        acc[dt] = mfma16(pa, vf, acc[dt]);
      }
    }
    __syncthreads();
  }

  #pragma unroll
  for (int j = 0; j < 4; ++j) {
    float rs = lsum[j];
    rs += __shfl_xor(rs, 1);
    rs += __shfl_xor(rs, 2);
    rs += __shfl_xor(rs, 4);
    rs += __shfl_xor(rs, 8);
    float invl = 1.0f / rs;
    size_t base = (size_t)(qw0 + g * 4 + j) * HIDDEN + h * HD;
    #pragma unroll
    for (int dt = 0; dt < 8; ++dt)
      O[base + dt * 16 + li] = (bf16)(acc[dt][j] * invl);
  }
}

// ---------------- launcher --------------------------------------------------
extern "C" void kernel_launch(void* const* d_in, const int* in_sizes, int n_in,
                              void* d_out, int out_size, void* d_ws, size_t ws_size,
                              hipStream_t stream) {
  const float* X  = (const float*)d_in[0];
  const float* qw = (const float*)d_in[1];
  const float* kw = (const float*)d_in[2];
  const float* vw = (const float*)d_in[3];
  const float* ow = (const float*)d_in[4];
  const int* pos = (const int*)d_in[5];
  const int* cu  = (const int*)d_in[6];
  int T = in_sizes[0] / HIDDEN;     // 8192
  int B = in_sizes[6] - 1;          // 4
  float* out = (float*)d_out;

  bf16* ws = (bf16*)d_ws;
  size_t off = 0;
  bf16* Xb   = ws + off; off += (size_t)T * HIDDEN;
  bf16* Qb   = ws + off; off += (size_t)T * HIDDEN;        // Q, then attn out
  bf16* Kb   = ws + off; off += (size_t)T * (NKV * HD);
  bf16* Vt   = ws + off; off += (size_t)T * (NKV * HD);
  bf16* wAll = ws + off; off += (size_t)3072 * HIDDEN;     // [qwT; kwT; vwT] stacked
  bf16* owT  = ws + off; off += (size_t)HIDDEN * HIDDEN;

  cast_f32_bf16<<<(T * HIDDEN / 4 + 255) / 256, 256, 0, stream>>>(X, Xb, T * HIDDEN / 4);

  dim3 tb(32, 8);
  transpose_cast<<<dim3(HIDDEN / 32, HIDDEN / 32), tb, 0, stream>>>(qw, wAll, HIDDEN, HIDDEN);
  transpose_cast<<<dim3(512 / 32, HIDDEN / 32), tb, 0, stream>>>(kw, wAll + (size_t)2048 * HIDDEN, HIDDEN, 512);
  transpose_cast<<<dim3(512 / 32, HIDDEN / 32), tb, 0, stream>>>(vw, wAll + (size_t)2560 * HIDDEN, HIDDEN, 512);
  transpose_cast<<<dim3(HIDDEN / 32, HIDDEN / 32), tb, 0, stream>>>(ow, owT, HIDDEN, HIDDEN);

  // fused QKV projection: C(T x 3072) = Xb * wAll^T, split epilogue
  gemm256<<<(T / 256) * (3072 / 256), 512, 0, stream>>>(Xb, wAll, Qb, Kb, Vt, T, 3072, HIDDEN, 3);

  rope_kernel<<<(T * NHEADS * 64 + 255) / 256, 256, 0, stream>>>(Qb, pos, T, NHEADS);
  rope_kernel<<<(T * NKV * 64 + 255) / 256, 256, 0, stream>>>(Kb, pos, T, NKV);

  attn_kernel<<<(T / 64) * NHEADS, 256, 0, stream>>>(Qb, Kb, Vt, pos, cu, Qb, T, B);

  // O-projection (fp32 out)
  gemm256<<<(T / 256) * (HIDDEN / 256), 512, 0, stream>>>(Qb, owT, out, nullptr, nullptr, T, HIDDEN, HIDDEN, 2);
}

// Round 6
// 375.648 us; speedup vs baseline: 1.4083x; 1.0131x over previous
//
#include <hip/hip_runtime.h>
#include <hip/hip_bf16.h>
#include <cstdint>
#include <cstddef>

typedef __bf16 bf16;
typedef __bf16 bf16x2 __attribute__((ext_vector_type(2)));
typedef __bf16 bf16x8 __attribute__((ext_vector_type(8)));
typedef float  f32x4  __attribute__((ext_vector_type(4)));

#define HIDDEN 2048
#define NHEADS 16
#define NKV    4
#define HD     128
#define WINDOW 512

// async global->LDS, 16B per lane; LDS dest is wave-uniform base + lane*16
__device__ __forceinline__ void gld16(const void* g, void* s) {
  __builtin_amdgcn_global_load_lds((const __attribute__((address_space(1))) void*)g,
                                   (__attribute__((address_space(3))) void*)s, 16, 0, 0);
}

__device__ __forceinline__ f32x4 mfma16(bf16x8 a, bf16x8 b, f32x4 c) {
  return __builtin_amdgcn_mfma_f32_16x16x32_bf16(a, b, c, 0, 0, 0);
}

__device__ __forceinline__ void barrier_raw() {
  asm volatile("" ::: "memory");
  __builtin_amdgcn_s_barrier();
  asm volatile("" ::: "memory");
}

// ---------------- cast fp32 -> bf16, 4 elems/thread -------------------------
__global__ __launch_bounds__(256) void cast_f32_bf16(const float* __restrict__ in,
                                                     bf16* __restrict__ out, int n4) {
  int i = blockIdx.x * 256 + threadIdx.x;
  if (i >= n4) return;
  f32x4 v = *(const f32x4*)(in + (size_t)i * 4);
  bf16x2 a, b;
  a[0] = (bf16)v[0]; a[1] = (bf16)v[1];
  b[0] = (bf16)v[2]; b[1] = (bf16)v[3];
  *(bf16x2*)(out + (size_t)i * 4)     = a;
  *(bf16x2*)(out + (size_t)i * 4 + 2) = b;
}

// ---------------- transpose+cast: fp32 (R x C) -> bf16 (C x R) --------------
__global__ __launch_bounds__(256) void transpose_cast(const float* __restrict__ in,
                                                      bf16* __restrict__ out, int R, int C) {
  __shared__ float tile[32][33];
  int c0 = blockIdx.x * 32, r0 = blockIdx.y * 32;
  int tx = threadIdx.x, ty = threadIdx.y;
  #pragma unroll
  for (int i = 0; i < 4; ++i)
    tile[ty + i * 8][tx] = in[(size_t)(r0 + ty + i * 8) * C + c0 + tx];
  __syncthreads();
  #pragma unroll
  for (int i = 0; i < 4; ++i)
    out[(size_t)(c0 + ty + i * 8) * R + r0 + tx] = (bf16)tile[tx][ty + i * 8];
}

// ======================= 128x128 GEMM (K/V projections) =====================
__device__ __forceinline__ void stage128x32(const bf16* __restrict__ A,
                                            const bf16* __restrict__ Bt,
                                            bf16* sA, bf16* sB,
                                            int m0, int n0, int K, int kt, int tid) {
  int wbase = tid & ~63;
  #pragma unroll
  for (int r = 0; r < 2; ++r) {
    int e = (r * 256 + tid) * 8;
    int row = e >> 5, col = e & 31;
    gld16(A  + (size_t)(m0 + row) * K + (size_t)kt * 32 + col,
          sA + (size_t)(r * 256 + wbase) * 8);
    gld16(Bt + (size_t)(n0 + row) * K + (size_t)kt * 32 + col,
          sB + (size_t)(r * 256 + wbase) * 8);
  }
}

__global__ __launch_bounds__(256) void gemm_bt(const bf16* __restrict__ A,
                                               const bf16* __restrict__ Bt,
                                               void* __restrict__ Cv,
                                               int M, int N, int K, int outMode) {
  __shared__ bf16 sA[2][128 * 32];
  __shared__ bf16 sB[2][128 * 32];
  int nb = N >> 7;
  int bm = (int)blockIdx.x / nb, bn = (int)blockIdx.x % nb;
  int m0 = bm << 7, n0 = bn << 7;
  int tid = threadIdx.x;
  int lane = tid & 63, w = tid >> 6;
  int li = lane & 15, g = lane >> 4, g8 = g * 8;
  int wm = w >> 1, wn = w & 1;
  f32x4 acc[4][4] = {};
  int NT = K >> 5;

  stage128x32(A, Bt, sA[0], sB[0], m0, n0, K, 0, tid);
  __syncthreads();
  for (int kt = 0; kt < NT; ++kt) {
    int cur = kt & 1;
    if (kt + 1 < NT)
      stage128x32(A, Bt, sA[cur ^ 1], sB[cur ^ 1], m0, n0, K, kt + 1, tid);
    bf16x8 af[4], bv[4];
    #pragma unroll
    for (int mt = 0; mt < 4; ++mt)
      af[mt] = *(const bf16x8*)&sA[cur][(wm * 64 + mt * 16 + li) * 32 + g8];
    #pragma unroll
    for (int nt = 0; nt < 4; ++nt)
      bv[nt] = *(const bf16x8*)&sB[cur][(wn * 64 + nt * 16 + li) * 32 + g8];
    #pragma unroll
    for (int mt = 0; mt < 4; ++mt)
      #pragma unroll
      for (int nt = 0; nt < 4; ++nt)
        acc[mt][nt] = mfma16(af[mt], bv[nt], acc[mt][nt]);
    __syncthreads();
  }
  #pragma unroll
  for (int mt = 0; mt < 4; ++mt)
    #pragma unroll
    for (int nt = 0; nt < 4; ++nt)
      #pragma unroll
      for (int j = 0; j < 4; ++j) {
        int row = m0 + wm * 64 + mt * 16 + g * 4 + j;
        int col = n0 + wn * 64 + nt * 16 + li;
        float v = acc[mt][nt][j];
        if (outMode == 0)      ((bf16*)Cv)[(size_t)row * N + col] = (bf16)v;
        else if (outMode == 1) ((bf16*)Cv)[(size_t)col * M + row] = (bf16)v;  // C^T (Vt)
        else                   ((float*)Cv)[(size_t)row * N + col] = v;
      }
}

// ======================= 256x256 8-wave pipelined GEMM ======================
// BM=BN=256, BK=64, 512 threads (2x4 waves, each owns 128x64 of C).
// Quadrant-aligned staging; issue order per K-tile: A0, B0, B1, A1 (one per
// phase). Counted vmcnt(6) keeps 3 half-tiles in flight. One barrier per
// phase; phase 3 barrier-free. 128 KiB LDS -> 1 block/CU: grid MUST be a
// multiple-of-8 and <= 256 for a single clean dispatch round.
template<int RSP>  // 64 for A halves, 32 for B halves
__device__ __forceinline__ void stage_quad(const bf16* __restrict__ G,
                                           bf16* __restrict__ sbuf,
                                           int grow0, int K, int k0, int half, int tid) {
  int w = tid >> 6, lane = tid & 63;
  int rl = lane >> 3;                         // row within the 8-row group
  int col = ((lane & 7) ^ rl) * 8;            // inverse-swizzled SOURCE col (rule #21)
  #pragma unroll
  for (int r = 0; r < 2; ++r) {
    int lr0 = r * 64 + w * 8;                 // multiple of 8, 0..120
    int row0 = (lr0 & (RSP - 1)) + half * RSP + (lr0 / RSP) * 2 * RSP;
    gld16(G + (size_t)(grow0 + row0 + rl) * K + k0 + col,
          sbuf + row0 * 64);                  // wave-uniform linear LDS dest
  }
}

// outMode: 0 = bf16 row-major; 2 = fp32 row-major
__global__ __launch_bounds__(512, 2) void gemm256(const bf16* __restrict__ A,
                                                  const bf16* __restrict__ Bt,
                                                  void* __restrict__ Cv,
                                                  int M, int N, int K, int outMode) {
  __shared__ bf16 sA[2][256 * 64];
  __shared__ bf16 sB[2][256 * 64];
  int nb = N >> 8;
  // XCD-aware bijective swizzle (grid is a multiple of 8)
  int cpx = (int)gridDim.x >> 3;
  int bid = (int)blockIdx.x;
  int swzb = (bid & 7) * cpx + (bid >> 3);
  int bm = swzb / nb, bn = swzb % nb;
  int m0 = bm << 8, n0 = bn << 8;
  int tid = threadIdx.x, lane = tid & 63, w = tid >> 6;
  int li = lane & 15, g = lane >> 4;
  int wm = w >> 2, wn = w & 3;                // 2 x 4 wave grid
  int swz = (li & 7);

  f32x4 acc[8][4] = {};
  bf16x8 af[4][2];       // A frags for current mh
  bf16x8 bv[2][2][2];    // B frags, both nh halves: [nh][nf][ks]

  int NT = K >> 6;

  // prologue: tile 0 in consumption order A0, B0, B1, A1
  stage_quad<64>(A,  sA[0], m0, K, 0, 0, tid);
  stage_quad<32>(Bt, sB[0], n0, K, 0, 0, tid);
  stage_quad<32>(Bt, sB[0], n0, K, 0, 1, tid);
  stage_quad<64>(A,  sA[0], m0, K, 0, 1, tid);

#define VMW(n) asm volatile("s_waitcnt vmcnt(" #n ")" ::: "memory")
#define LOAD_A256(mh) { _Pragma("unroll") for (int mf = 0; mf < 4; ++mf) \
  _Pragma("unroll") for (int ks = 0; ks < 2; ++ks) { \
    int row = wm * 128 + (mh) * 64 + mf * 16 + li; \
    af[mf][ks] = *(const bf16x8*)&sA[cur][row * 64 + ((ks * 4 + g) ^ swz) * 8]; } }
#define LOAD_B256(nh) { _Pragma("unroll") for (int nf = 0; nf < 2; ++nf) \
  _Pragma("unroll") for (int ks = 0; ks < 2; ++ks) { \
    int row = wn * 64 + (nh) * 32 + nf * 16 + li; \
    bv[nh][nf][ks] = *(const bf16x8*)&sB[cur][row * 64 + ((ks * 4 + g) ^ swz) * 8]; } }
#define LGKM0() { asm volatile("s_waitcnt lgkmcnt(0)" ::: "memory"); \
  __builtin_amdgcn_sched_barrier(0); }
#define MFMA_PH(mh, nh) { \
  __builtin_amdgcn_s_setprio(1); \
  _Pragma("unroll") for (int mf = 0; mf < 4; ++mf) \
  _Pragma("unroll") for (int nf = 0; nf < 2; ++nf) \
  _Pragma("unroll") for (int ks = 0; ks < 2; ++ks) \
    acc[(mh) * 4 + mf][(nh) * 2 + nf] = \
      mfma16(af[mf][ks], bv[nh][nf][ks], acc[(mh) * 4 + mf][(nh) * 2 + nf]); \
  __builtin_amdgcn_s_setprio(0); }

  int cur = 0;
  for (int t = 0; t < NT; ++t) {
    int nxt = cur ^ 1;
    bool pre = (t + 1 < NT);
    int k1 = (t + 1) << 6;
    // ---- phase 0: quadrant (mh0, nh0); needs A0,B0 (issued >=3 phases ago)
    if (pre) { stage_quad<64>(A, sA[nxt], m0, K, k1, 0, tid); VMW(6); }
    else     { VMW(4); }
    barrier_raw();
    LOAD_A256(0); LOAD_B256(0);
    LGKM0();
    MFMA_PH(0, 0);
    // ---- phase 1: quadrant (mh0, nh1); needs B1
    if (pre) { stage_quad<32>(Bt, sB[nxt], n0, K, k1, 0, tid); VMW(6); }
    else     { VMW(2); }
    barrier_raw();
    LOAD_B256(1);
    LGKM0();
    MFMA_PH(0, 1);
    // ---- phase 2: quadrant (mh1, nh1); needs A1
    if (pre) { stage_quad<32>(Bt, sB[nxt], n0, K, k1, 1, tid); VMW(6); }
    else     { VMW(0); }
    barrier_raw();
    LOAD_A256(1);
    LGKM0();
    MFMA_PH(1, 1);
    // ---- phase 3: quadrant (mh1, nh0); operands already in registers
    if (pre) stage_quad<64>(A, sA[nxt], m0, K, k1, 1, tid);
    MFMA_PH(1, 0);
    cur = nxt;
  }
#undef VMW
#undef LOAD_A256
#undef LOAD_B256
#undef LGKM0
#undef MFMA_PH

  #pragma unroll
  for (int mi = 0; mi < 8; ++mi)
    #pragma unroll
    for (int ni = 0; ni < 4; ++ni)
      #pragma unroll
      for (int j = 0; j < 4; ++j) {
        int row = m0 + wm * 128 + mi * 16 + g * 4 + j;
        int col = n0 + wn * 64 + ni * 16 + li;
        float v = acc[mi][ni][j];
        if (outMode == 2) ((float*)Cv)[(size_t)row * N + col] = v;
        else              ((bf16*)Cv)[(size_t)row * N + col] = (bf16)v;
      }
}

// ---------------- RoPE in place: X (T x heads*128), interleaved pairs -------
__global__ __launch_bounds__(256) void rope_kernel(bf16* __restrict__ X,
                                                   const int* __restrict__ pos,
                                                   int T, int heads) {
  int idx = blockIdx.x * 256 + threadIdx.x;
  int total = T * heads * 64;
  if (idx >= total) return;
  int i = idx & 63;
  int rest = idx >> 6;
  int hh = rest % heads;
  int t = rest / heads;
  float inv = expf((float)i * (-9.210340371976184f / 64.0f)); // theta^(-i/64)
  float ang = (float)pos[t] * inv;
  float s, c;
  sincosf(ang, &s, &c);
  bf16* p = X + ((size_t)t * heads + hh) * HD + 2 * i;
  bf16x2 xv = *(const bf16x2*)p;
  float xe = (float)xv[0], xo = (float)xv[1];
  bf16x2 r;
  r[0] = (bf16)(xe * c - xo * s);
  r[1] = (bf16)(xe * s + xo * c);
  *(bf16x2*)p = r;
}

// ---------------- sliding-window GQA flash attention ------------------------
__global__ __launch_bounds__(256) void attn_kernel(const bf16* __restrict__ Q,
                                                   const bf16* __restrict__ Kb,
                                                   const bf16* __restrict__ Vt,
                                                   const int* __restrict__ pos,
                                                   const int* __restrict__ cu,
                                                   bf16* __restrict__ O, int T, int B) {
  __shared__ bf16 sK[32 * 128];    // data(row,chunk) stored at chunk^(row&7); 16B chunks
  __shared__ bf16 sVt2[64 * 64];   // LDS row r: d=2r (chunks 0-3), d=2r+1 (chunks 4-7), ^(r&7)
  __shared__ bf16 sP[4][16 * 40];  // per-wave P tile, stride 40 elems = conflict-free
  int bid = blockIdx.x;
  int h  = bid & (NHEADS - 1);
  int qb = bid >> 4;
  int q0 = qb * 64;
  int kvh = h >> 2;
  int tid = threadIdx.x, lane = tid & 63, w = tid >> 6;
  int li = lane & 15, g = lane >> 4, g8 = g * 8;
  int qw0 = q0 + w * 16;

  int seq_start = 0, seq_end = T;
  for (int b = 0; b < B; ++b) {
    int a = cu[b], e = cu[b + 1];
    if (q0 >= a && q0 < e) { seq_start = a; seq_end = e; }
  }

  bf16x8 qf[4];
  #pragma unroll
  for (int kd = 0; kd < 4; ++kd)
    qf[kd] = *(const bf16x8*)(Q + (size_t)(qw0 + li) * HIDDEN + h * HD + kd * 32 + g8);

  int pq[4];
  #pragma unroll
  for (int j = 0; j < 4; ++j) pq[j] = pos[qw0 + g * 4 + j];
  int pqw_min = pos[qw0], pqw_max = pos[qw0 + 15];

  float lsum[4] = {0.f, 0.f, 0.f, 0.f};
  f32x4 acc[8] = {};

  int kstart = q0 - WINDOW;
  if (kstart < seq_start) kstart = seq_start;
  int kend = q0 + 64;
  if (kend > seq_end) kend = seq_end;
  const float scale = 0.08838834764831845f;

  for (int kb = kstart; kb < kend; kb += 32) {
    int wbase = tid & ~63;
    #pragma unroll
    for (int r = 0; r < 2; ++r) {
      int n = r * 256 + tid;
      int krow = n >> 4, kc = (n & 15) ^ (krow & 7);
      gld16(Kb + (size_t)(kb + krow) * (NKV * HD) + kvh * HD + kc * 8,
            sK + (size_t)(r * 256 + wbase) * 8);
      int vr = n >> 3, vc = (n & 7) ^ (vr & 7);
      int vd = 2 * vr + (vc >> 2), vkey = (vc & 3) * 8;
      gld16(Vt + (size_t)(kvh * HD + vd) * T + kb + vkey,
            sVt2 + (size_t)(r * 256 + wbase) * 8);
    }
    __syncthreads();

    int pkf = pos[kb], pkl = pos[kb + 31];
    bool active = !(pkf > pqw_max || pkl < pqw_min - WINDOW);
    if (active) {
      f32x4 s0v = {0.f, 0.f, 0.f, 0.f}, s1v = {0.f, 0.f, 0.f, 0.f};
      #pragma unroll
      for (int kd = 0; kd < 4; ++kd) {
        int chunk = kd * 4 + g;
        int c0 = chunk ^ (li & 7);
        bf16x8 b0 = *(const bf16x8*)&sK[li * 128 + c0 * 8];
        bf16x8 b1 = *(const bf16x8*)&sK[(16 + li) * 128 + c0 * 8];
        s0v = mfma16(qf[kd], b0, s0v);
        s1v = mfma16(qf[kd], b1, s1v);
      }
      int pk0 = pos[kb + li], pk1 = pos[kb + 16 + li];
      #pragma unroll
      for (int j = 0; j < 4; ++j) {
        int d0 = pq[j] - pk0, d1 = pq[j] - pk1;
        float p0 = (d0 >= 0 && d0 <= WINDOW) ? __expf(s0v[j] * scale) : 0.f;
        float p1 = (d1 >= 0 && d1 <= WINDOW) ? __expf(s1v[j] * scale) : 0.f;
        lsum[j] += p0 + p1;
        sP[w][(g * 4 + j) * 40 + li]      = (bf16)p0;
        sP[w][(g * 4 + j) * 40 + 16 + li] = (bf16)p1;
      }
      bf16x8 pa = *(const bf16x8*)&sP[w][li * 40 + g8];
      #pragma unroll
      for (int dt = 0; dt < 8; ++dt) {
        int d = dt * 16 + li;
        int vr = d >> 1;
        int vc = ((d & 1) * 4 + g) ^ (vr & 7);
        bf16x8 vf = *(const bf16x8*)&sVt2[vr * 64 + vc * 8];
        acc[dt] = mfma16(pa, vf, acc[dt]);
      }
    }
    __syncthreads();
  }

  #pragma unroll
  for (int j = 0; j < 4; ++j) {
    float rs = lsum[j];
    rs += __shfl_xor(rs, 1);
    rs += __shfl_xor(rs, 2);
    rs += __shfl_xor(rs, 4);
    rs += __shfl_xor(rs, 8);
    float invl = 1.0f / rs;
    size_t base = (size_t)(qw0 + g * 4 + j) * HIDDEN + h * HD;
    #pragma unroll
    for (int dt = 0; dt < 8; ++dt)
      O[base + dt * 16 + li] = (bf16)(acc[dt][j] * invl);
  }
}

// ---------------- launcher --------------------------------------------------
extern "C" void kernel_launch(void* const* d_in, const int* in_sizes, int n_in,
                              void* d_out, int out_size, void* d_ws, size_t ws_size,
                              hipStream_t stream) {
  const float* X  = (const float*)d_in[0];
  const float* qw = (const float*)d_in[1];
  const float* kw = (const float*)d_in[2];
  const float* vw = (const float*)d_in[3];
  const float* ow = (const float*)d_in[4];
  const int* pos = (const int*)d_in[5];
  const int* cu  = (const int*)d_in[6];
  int T = in_sizes[0] / HIDDEN;     // 8192
  int B = in_sizes[6] - 1;          // 4
  float* out = (float*)d_out;

  bf16* ws = (bf16*)d_ws;
  size_t off = 0;
  bf16* Xb   = ws + off; off += (size_t)T * HIDDEN;
  bf16* Qb   = ws + off; off += (size_t)T * HIDDEN;        // Q, then attn out
  bf16* Kb   = ws + off; off += (size_t)T * (NKV * HD);
  bf16* Vt   = ws + off; off += (size_t)T * (NKV * HD);
  bf16* qwT  = ws + off; off += (size_t)HIDDEN * HIDDEN;
  bf16* kwT  = ws + off; off += (size_t)HIDDEN * (NKV * HD);
  bf16* vwT  = ws + off; off += (size_t)HIDDEN * (NKV * HD);
  bf16* owT  = ws + off; off += (size_t)HIDDEN * HIDDEN;

  cast_f32_bf16<<<(T * HIDDEN / 4 + 255) / 256, 256, 0, stream>>>(X, Xb, T * HIDDEN / 4);

  dim3 tb(32, 8);
  transpose_cast<<<dim3(HIDDEN / 32, HIDDEN / 32), tb, 0, stream>>>(qw, qwT, HIDDEN, HIDDEN);
  transpose_cast<<<dim3(512 / 32, HIDDEN / 32), tb, 0, stream>>>(kw, kwT, HIDDEN, 512);
  transpose_cast<<<dim3(512 / 32, HIDDEN / 32), tb, 0, stream>>>(vw, vwT, HIDDEN, 512);
  transpose_cast<<<dim3(HIDDEN / 32, HIDDEN / 32), tb, 0, stream>>>(ow, owT, HIDDEN, HIDDEN);

  // Q-projection: 256x256 pipelined GEMM, grid = 32*8 = 256 (one clean round)
  gemm256<<<(T / 256) * (HIDDEN / 256), 512, 0, stream>>>(Xb, qwT, Qb, T, HIDDEN, HIDDEN, 0);
  // K/V projections: 128x128 kernel, 256 blocks each (high occupancy)
  gemm_bt<<<(T / 128) * (512 / 128), 256, 0, stream>>>(Xb, kwT, Kb, T, 512, HIDDEN, 0);
  gemm_bt<<<(T / 128) * (512 / 128), 256, 0, stream>>>(Xb, vwT, Vt, T, 512, HIDDEN, 1);

  rope_kernel<<<(T * NHEADS * 64 + 255) / 256, 256, 0, stream>>>(Qb, pos, T, NHEADS);
  rope_kernel<<<(T * NKV * 64 + 255) / 256, 256, 0, stream>>>(Kb, pos, T, NKV);

  attn_kernel<<<(T / 64) * NHEADS, 256, 0, stream>>>(Qb, Kb, Vt, pos, cu, Qb, T, B);

  // O-projection (fp32 out), grid 256
  gemm256<<<(T / 256) * (HIDDEN / 256), 512, 0, stream>>>(Qb, owT, out, T, HIDDEN, HIDDEN, 2);
}

// Round 7
// 371.745 us; speedup vs baseline: 1.4231x; 1.0105x over previous
//
#include <hip/hip_runtime.h>
#include <hip/hip_bf16.h>
#include <cstdint>
#include <cstddef>

typedef __bf16 bf16;
typedef __bf16 bf16x2 __attribute__((ext_vector_type(2)));
typedef __bf16 bf16x8 __attribute__((ext_vector_type(8)));
typedef float  f32x4  __attribute__((ext_vector_type(4)));

#define HIDDEN 2048
#define NHEADS 16
#define NKV    4
#define HD     128
#define WINDOW 512

// async global->LDS, 16B per lane; LDS dest is wave-uniform base + lane*16
__device__ __forceinline__ void gld16(const void* g, void* s) {
  __builtin_amdgcn_global_load_lds((const __attribute__((address_space(1))) void*)g,
                                   (__attribute__((address_space(3))) void*)s, 16, 0, 0);
}

__device__ __forceinline__ f32x4 mfma16(bf16x8 a, bf16x8 b, f32x4 c) {
  return __builtin_amdgcn_mfma_f32_16x16x32_bf16(a, b, c, 0, 0, 0);
}

__device__ __forceinline__ void barrier_raw() {
  asm volatile("" ::: "memory");
  __builtin_amdgcn_s_barrier();
  asm volatile("" ::: "memory");
}

// ---------------- cast fp32 -> bf16, 4 elems/thread -------------------------
__global__ __launch_bounds__(256) void cast_f32_bf16(const float* __restrict__ in,
                                                     bf16* __restrict__ out, int n4) {
  int i = blockIdx.x * 256 + threadIdx.x;
  if (i >= n4) return;
  f32x4 v = *(const f32x4*)(in + (size_t)i * 4);
  bf16x2 a, b;
  a[0] = (bf16)v[0]; a[1] = (bf16)v[1];
  b[0] = (bf16)v[2]; b[1] = (bf16)v[3];
  *(bf16x2*)(out + (size_t)i * 4)     = a;
  *(bf16x2*)(out + (size_t)i * 4 + 2) = b;
}

// ---------------- transpose+cast: fp32 (R x C) -> bf16 (C x R) --------------
__global__ __launch_bounds__(256) void transpose_cast(const float* __restrict__ in,
                                                      bf16* __restrict__ out, int R, int C) {
  __shared__ float tile[32][33];
  int c0 = blockIdx.x * 32, r0 = blockIdx.y * 32;
  int tx = threadIdx.x, ty = threadIdx.y;
  #pragma unroll
  for (int i = 0; i < 4; ++i)
    tile[ty + i * 8][tx] = in[(size_t)(r0 + ty + i * 8) * C + c0 + tx];
  __syncthreads();
  #pragma unroll
  for (int i = 0; i < 4; ++i)
    out[(size_t)(c0 + ty + i * 8) * R + r0 + tx] = (bf16)tile[tx][ty + i * 8];
}

// ======================= 128x128 GEMM (K/V projections) =====================
__device__ __forceinline__ void stage128x32(const bf16* __restrict__ A,
                                            const bf16* __restrict__ Bt,
                                            bf16* sA, bf16* sB,
                                            int m0, int n0, int K, int kt, int tid) {
  int wbase = tid & ~63;
  #pragma unroll
  for (int r = 0; r < 2; ++r) {
    int e = (r * 256 + tid) * 8;
    int row = e >> 5, col = e & 31;
    gld16(A  + (size_t)(m0 + row) * K + (size_t)kt * 32 + col,
          sA + (size_t)(r * 256 + wbase) * 8);
    gld16(Bt + (size_t)(n0 + row) * K + (size_t)kt * 32 + col,
          sB + (size_t)(r * 256 + wbase) * 8);
  }
}

__global__ __launch_bounds__(256) void gemm_bt(const bf16* __restrict__ A,
                                               const bf16* __restrict__ Bt,
                                               void* __restrict__ Cv,
                                               int M, int N, int K, int outMode) {
  __shared__ bf16 sA[2][128 * 32];
  __shared__ bf16 sB[2][128 * 32];
  int nb = N >> 7;
  int bm = (int)blockIdx.x / nb, bn = (int)blockIdx.x % nb;
  int m0 = bm << 7, n0 = bn << 7;
  int tid = threadIdx.x;
  int lane = tid & 63, w = tid >> 6;
  int li = lane & 15, g = lane >> 4, g8 = g * 8;
  int wm = w >> 1, wn = w & 1;
  f32x4 acc[4][4] = {};
  int NT = K >> 5;

  stage128x32(A, Bt, sA[0], sB[0], m0, n0, K, 0, tid);
  __syncthreads();
  for (int kt = 0; kt < NT; ++kt) {
    int cur = kt & 1;
    if (kt + 1 < NT)
      stage128x32(A, Bt, sA[cur ^ 1], sB[cur ^ 1], m0, n0, K, kt + 1, tid);
    bf16x8 af[4], bv[4];
    #pragma unroll
    for (int mt = 0; mt < 4; ++mt)
      af[mt] = *(const bf16x8*)&sA[cur][(wm * 64 + mt * 16 + li) * 32 + g8];
    #pragma unroll
    for (int nt = 0; nt < 4; ++nt)
      bv[nt] = *(const bf16x8*)&sB[cur][(wn * 64 + nt * 16 + li) * 32 + g8];
    #pragma unroll
    for (int mt = 0; mt < 4; ++mt)
      #pragma unroll
      for (int nt = 0; nt < 4; ++nt)
        acc[mt][nt] = mfma16(af[mt], bv[nt], acc[mt][nt]);
    __syncthreads();
  }
  #pragma unroll
  for (int mt = 0; mt < 4; ++mt)
    #pragma unroll
    for (int nt = 0; nt < 4; ++nt)
      #pragma unroll
      for (int j = 0; j < 4; ++j) {
        int row = m0 + wm * 64 + mt * 16 + g * 4 + j;
        int col = n0 + wn * 64 + nt * 16 + li;
        float v = acc[mt][nt][j];
        if (outMode == 0)      ((bf16*)Cv)[(size_t)row * N + col] = (bf16)v;
        else if (outMode == 1) ((bf16*)Cv)[(size_t)col * M + row] = (bf16)v;  // C^T (Vt)
        else                   ((float*)Cv)[(size_t)row * N + col] = v;
      }
}

// ======================= 256x256 8-wave pipelined GEMM ======================
// BM=BN=256, BK=64, 512 threads (2x4 waves, each owns 128x64 of C).
// ONE vmcnt(0)+barrier per K-tile (the youngest awaited load has >=2 MFMA
// regions of slack, so the drain costs ~nothing). All stages issued
// post-barrier (pre-barrier staging would race slow waves' reads of the
// same buffer). ds_reads batched up-front with a counted lgkmcnt(4), B1's
// reads float through the first MFMA region. Quadrant order 00->01->11->10
// reuses A-half regs. sched_barrier(0) pins issue order (rule #18).
template<int RSP>  // 64 for A halves, 32 for B halves
__device__ __forceinline__ void stage_quad(const bf16* __restrict__ G,
                                           bf16* __restrict__ sbuf,
                                           int grow0, int K, int k0, int half, int tid) {
  int w = tid >> 6, lane = tid & 63;
  int rl = lane >> 3;                         // row within the 8-row group
  int col = ((lane & 7) ^ rl) * 8;            // inverse-swizzled SOURCE col (rule #21)
  #pragma unroll
  for (int r = 0; r < 2; ++r) {
    int lr0 = r * 64 + w * 8;                 // multiple of 8, 0..120
    int row0 = (lr0 & (RSP - 1)) + half * RSP + (lr0 / RSP) * 2 * RSP;
    gld16(G + (size_t)(grow0 + row0 + rl) * K + k0 + col,
          sbuf + row0 * 64);                  // wave-uniform linear LDS dest
  }
}

// outMode: 0 = bf16 row-major; 2 = fp32 row-major
__global__ __launch_bounds__(512, 2) void gemm256(const bf16* __restrict__ A,
                                                  const bf16* __restrict__ Bt,
                                                  void* __restrict__ Cv,
                                                  int M, int N, int K, int outMode) {
  __shared__ bf16 sA[2][256 * 64];
  __shared__ bf16 sB[2][256 * 64];
  int nb = N >> 8;
  // XCD-aware bijective swizzle (grid is a multiple of 8)
  int cpx = (int)gridDim.x >> 3;
  int bid = (int)blockIdx.x;
  int swzb = (bid & 7) * cpx + (bid >> 3);
  int bm = swzb / nb, bn = swzb % nb;
  int m0 = bm << 8, n0 = bn << 8;
  int tid = threadIdx.x, lane = tid & 63, w = tid >> 6;
  int li = lane & 15, g = lane >> 4;
  int wm = w >> 2, wn = w & 3;                // 2 x 4 wave grid
  int swz = (li & 7);

  f32x4 acc[8][4] = {};
  bf16x8 af[4][2];       // A frags for current mh
  bf16x8 bv[2][2][2];    // B frags, both nh halves: [nh][nf][ks]

  int NT = K >> 6;

  // prologue: stage tile 0 (A0, B0, B1, A1)
  stage_quad<64>(A,  sA[0], m0, K, 0, 0, tid);
  stage_quad<32>(Bt, sB[0], n0, K, 0, 0, tid);
  stage_quad<32>(Bt, sB[0], n0, K, 0, 1, tid);
  stage_quad<64>(A,  sA[0], m0, K, 0, 1, tid);

#define VMW(n) asm volatile("s_waitcnt vmcnt(" #n ")" ::: "memory")
#define SBAR() __builtin_amdgcn_sched_barrier(0)
#define LGKM(n) { asm volatile("s_waitcnt lgkmcnt(" #n ")" ::: "memory"); \
  __builtin_amdgcn_sched_barrier(0); }
#define LOAD_A256(mh) { _Pragma("unroll") for (int mf = 0; mf < 4; ++mf) \
  _Pragma("unroll") for (int ks = 0; ks < 2; ++ks) { \
    int row = wm * 128 + (mh) * 64 + mf * 16 + li; \
    af[mf][ks] = *(const bf16x8*)&sA[cur][row * 64 + ((ks * 4 + g) ^ swz) * 8]; } }
#define LOAD_B256(nh) { _Pragma("unroll") for (int nf = 0; nf < 2; ++nf) \
  _Pragma("unroll") for (int ks = 0; ks < 2; ++ks) { \
    int row = wn * 64 + (nh) * 32 + nf * 16 + li; \
    bv[nh][nf][ks] = *(const bf16x8*)&sB[cur][row * 64 + ((ks * 4 + g) ^ swz) * 8]; } }
#define MFMA_PH(mh, nh) { \
  __builtin_amdgcn_s_setprio(1); \
  _Pragma("unroll") for (int mf = 0; mf < 4; ++mf) \
  _Pragma("unroll") for (int nf = 0; nf < 2; ++nf) \
  _Pragma("unroll") for (int ks = 0; ks < 2; ++ks) \
    acc[(mh) * 4 + mf][(nh) * 2 + nf] = \
      mfma16(af[mf][ks], bv[nh][nf][ks], acc[(mh) * 4 + mf][(nh) * 2 + nf]); \
  __builtin_amdgcn_s_setprio(0); }

  int cur = 0;
  for (int t = 0; t < NT; ++t) {
    int nxt = cur ^ 1;
    bool pre = (t + 1 < NT);
    int k1 = (t + 1) << 6;
    // tile gate: all of tile t resident (its youngest load was issued
    // >=2 MFMA regions ago), then sync. No other waits/barriers this tile.
    VMW(0);
    barrier_raw();
    if (pre) stage_quad<64>(A, sA[nxt], m0, K, k1, 0, tid);     // A0(t+1)
    LOAD_A256(0); LOAD_B256(0);                                 // 12 ds_read
    SBAR();
    LOAD_B256(1);                                               // 4 ds_read (youngest)
    if (pre) stage_quad<32>(Bt, sB[nxt], n0, K, k1, 0, tid);    // B0(t+1)
    LGKM(4);                                                    // A0+B0 frags ready
    MFMA_PH(0, 0);
    if (pre) stage_quad<32>(Bt, sB[nxt], n0, K, k1, 1, tid);    // B1(t+1)
    LGKM(0);                                                    // B1 frags ready
    MFMA_PH(0, 1);
    LOAD_A256(1);                                               // 8 ds_read (af reuse)
    if (pre) stage_quad<64>(A, sA[nxt], m0, K, k1, 1, tid);     // A1(t+1)
    LGKM(0);
    MFMA_PH(1, 1);
    MFMA_PH(1, 0);
    cur = nxt;
  }
#undef VMW
#undef SBAR
#undef LGKM
#undef LOAD_A256
#undef LOAD_B256
#undef MFMA_PH

  #pragma unroll
  for (int mi = 0; mi < 8; ++mi)
    #pragma unroll
    for (int ni = 0; ni < 4; ++ni)
      #pragma unroll
      for (int j = 0; j < 4; ++j) {
        int row = m0 + wm * 128 + mi * 16 + g * 4 + j;
        int col = n0 + wn * 64 + ni * 16 + li;
        float v = acc[mi][ni][j];
        if (outMode == 2) ((float*)Cv)[(size_t)row * N + col] = v;
        else              ((bf16*)Cv)[(size_t)row * N + col] = (bf16)v;
      }
}

// ---------------- RoPE in place: X (T x heads*128), interleaved pairs -------
__global__ __launch_bounds__(256) void rope_kernel(bf16* __restrict__ X,
                                                   const int* __restrict__ pos,
                                                   int T, int heads) {
  int idx = blockIdx.x * 256 + threadIdx.x;
  int total = T * heads * 64;
  if (idx >= total) return;
  int i = idx & 63;
  int rest = idx >> 6;
  int hh = rest % heads;
  int t = rest / heads;
  float inv = expf((float)i * (-9.210340371976184f / 64.0f)); // theta^(-i/64)
  float ang = (float)pos[t] * inv;
  float s, c;
  sincosf(ang, &s, &c);
  bf16* p = X + ((size_t)t * heads + hh) * HD + 2 * i;
  bf16x2 xv = *(const bf16x2*)p;
  float xe = (float)xv[0], xo = (float)xv[1];
  bf16x2 r;
  r[0] = (bf16)(xe * c - xo * s);
  r[1] = (bf16)(xe * s + xo * c);
  *(bf16x2*)p = r;
}

// ---------------- sliding-window GQA flash attention ------------------------
__global__ __launch_bounds__(256) void attn_kernel(const bf16* __restrict__ Q,
                                                   const bf16* __restrict__ Kb,
                                                   const bf16* __restrict__ Vt,
                                                   const int* __restrict__ pos,
                                                   const int* __restrict__ cu,
                                                   bf16* __restrict__ O, int T, int B) {
  __shared__ bf16 sK[32 * 128];    // data(row,chunk) stored at chunk^(row&7); 16B chunks
  __shared__ bf16 sVt2[64 * 64];   // LDS row r: d=2r (chunks 0-3), d=2r+1 (chunks 4-7), ^(r&7)
  __shared__ bf16 sP[4][16 * 40];  // per-wave P tile, stride 40 elems = conflict-free
  int bid = blockIdx.x;
  int h  = bid & (NHEADS - 1);
  int qb = bid >> 4;
  int q0 = qb * 64;
  int kvh = h >> 2;
  int tid = threadIdx.x, lane = tid & 63, w = tid >> 6;
  int li = lane & 15, g = lane >> 4, g8 = g * 8;
  int qw0 = q0 + w * 16;

  int seq_start = 0, seq_end = T;
  for (int b = 0; b < B; ++b) {
    int a = cu[b], e = cu[b + 1];
    if (q0 >= a && q0 < e) { seq_start = a; seq_end = e; }
  }

  bf16x8 qf[4];
  #pragma unroll
  for (int kd = 0; kd < 4; ++kd)
    qf[kd] = *(const bf16x8*)(Q + (size_t)(qw0 + li) * HIDDEN + h * HD + kd * 32 + g8);

  int pq[4];
  #pragma unroll
  for (int j = 0; j < 4; ++j) pq[j] = pos[qw0 + g * 4 + j];
  int pqw_min = pos[qw0], pqw_max = pos[qw0 + 15];

  float lsum[4] = {0.f, 0.f, 0.f, 0.f};
  f32x4 acc[8] = {};

  int kstart = q0 - WINDOW;
  if (kstart < seq_start) kstart = seq_start;
  int kend = q0 + 64;
  if (kend > seq_end) kend = seq_end;
  const float scale = 0.08838834764831845f;

  for (int kb = kstart; kb < kend; kb += 32) {
    int wbase = tid & ~63;
    #pragma unroll
    for (int r = 0; r < 2; ++r) {
      int n = r * 256 + tid;
      int krow = n >> 4, kc = (n & 15) ^ (krow & 7);
      gld16(Kb + (size_t)(kb + krow) * (NKV * HD) + kvh * HD + kc * 8,
            sK + (size_t)(r * 256 + wbase) * 8);
      int vr = n >> 3, vc = (n & 7) ^ (vr & 7);
      int vd = 2 * vr + (vc >> 2), vkey = (vc & 3) * 8;
      gld16(Vt + (size_t)(kvh * HD + vd) * T + kb + vkey,
            sVt2 + (size_t)(r * 256 + wbase) * 8);
    }
    __syncthreads();

    int pkf = pos[kb], pkl = pos[kb + 31];
    bool active = !(pkf > pqw_max || pkl < pqw_min - WINDOW);
    if (active) {
      f32x4 s0v = {0.f, 0.f, 0.f, 0.f}, s1v = {0.f, 0.f, 0.f, 0.f};
      #pragma unroll
      for (int kd = 0; kd < 4; ++kd) {
        int chunk = kd * 4 + g;
        int c0 = chunk ^ (li & 7);
        bf16x8 b0 = *(const bf16x8*)&sK[li * 128 + c0 * 8];
        bf16x8 b1 = *(const bf16x8*)&sK[(16 + li) * 128 + c0 * 8];
        s0v = mfma16(qf[kd], b0, s0v);
        s1v = mfma16(qf[kd], b1, s1v);
      }
      int pk0 = pos[kb + li], pk1 = pos[kb + 16 + li];
      #pragma unroll
      for (int j = 0; j < 4; ++j) {
        int d0 = pq[j] - pk0, d1 = pq[j] - pk1;
        float p0 = (d0 >= 0 && d0 <= WINDOW) ? __expf(s0v[j] * scale) : 0.f;
        float p1 = (d1 >= 0 && d1 <= WINDOW) ? __expf(s1v[j] * scale) : 0.f;
        lsum[j] += p0 + p1;
        sP[w][(g * 4 + j) * 40 + li]      = (bf16)p0;
        sP[w][(g * 4 + j) * 40 + 16 + li] = (bf16)p1;
      }
      bf16x8 pa = *(const bf16x8*)&sP[w][li * 40 + g8];
      #pragma unroll
      for (int dt = 0; dt < 8; ++dt) {
        int d = dt * 16 + li;
        int vr = d >> 1;
        int vc = ((d & 1) * 4 + g) ^ (vr & 7);
        bf16x8 vf = *(const bf16x8*)&sVt2[vr * 64 + vc * 8];
        acc[dt] = mfma16(pa, vf, acc[dt]);
      }
    }
    __syncthreads();
  }

  #pragma unroll
  for (int j = 0; j < 4; ++j) {
    float rs = lsum[j];
    rs += __shfl_xor(rs, 1);
    rs += __shfl_xor(rs, 2);
    rs += __shfl_xor(rs, 4);
    rs += __shfl_xor(rs, 8);
    float invl = 1.0f / rs;
    size_t base = (size_t)(qw0 + g * 4 + j) * HIDDEN + h * HD;
    #pragma unroll
    for (int dt = 0; dt < 8; ++dt)
      O[base + dt * 16 + li] = (bf16)(acc[dt][j] * invl);
  }
}

// ---------------- launcher --------------------------------------------------
extern "C" void kernel_launch(void* const* d_in, const int* in_sizes, int n_in,
                              void* d_out, int out_size, void* d_ws, size_t ws_size,
                              hipStream_t stream) {
  const float* X  = (const float*)d_in[0];
  const float* qw = (const float*)d_in[1];
  const float* kw = (const float*)d_in[2];
  const float* vw = (const float*)d_in[3];
  const float* ow = (const float*)d_in[4];
  const int* pos = (const int*)d_in[5];
  const int* cu  = (const int*)d_in[6];
  int T = in_sizes[0] / HIDDEN;     // 8192
  int B = in_sizes[6] - 1;          // 4
  float* out = (float*)d_out;

  bf16* ws = (bf16*)d_ws;
  size_t off = 0;
  bf16* Xb   = ws + off; off += (size_t)T * HIDDEN;
  bf16* Qb   = ws + off; off += (size_t)T * HIDDEN;        // Q, then attn out
  bf16* Kb   = ws + off; off += (size_t)T * (NKV * HD);
  bf16* Vt   = ws + off; off += (size_t)T * (NKV * HD);
  bf16* qwT  = ws + off; off += (size_t)HIDDEN * HIDDEN;
  bf16* kwT  = ws + off; off += (size_t)HIDDEN * (NKV * HD);
  bf16* vwT  = ws + off; off += (size_t)HIDDEN * (NKV * HD);
  bf16* owT  = ws + off; off += (size_t)HIDDEN * HIDDEN;

  cast_f32_bf16<<<(T * HIDDEN / 4 + 255) / 256, 256, 0, stream>>>(X, Xb, T * HIDDEN / 4);

  dim3 tb(32, 8);
  transpose_cast<<<dim3(HIDDEN / 32, HIDDEN / 32), tb, 0, stream>>>(qw, qwT, HIDDEN, HIDDEN);
  transpose_cast<<<dim3(512 / 32, HIDDEN / 32), tb, 0, stream>>>(kw, kwT, HIDDEN, 512);
  transpose_cast<<<dim3(512 / 32, HIDDEN / 32), tb, 0, stream>>>(vw, vwT, HIDDEN, 512);
  transpose_cast<<<dim3(HIDDEN / 32, HIDDEN / 32), tb, 0, stream>>>(ow, owT, HIDDEN, HIDDEN);

  // Q-projection: 256x256 pipelined GEMM, grid = 32*8 = 256 (one clean round)
  gemm256<<<(T / 256) * (HIDDEN / 256), 512, 0, stream>>>(Xb, qwT, Qb, T, HIDDEN, HIDDEN, 0);
  // K/V projections: 128x128 kernel, 256 blocks each (high occupancy)
  gemm_bt<<<(T / 128) * (512 / 128), 256, 0, stream>>>(Xb, kwT, Kb, T, 512, HIDDEN, 0);
  gemm_bt<<<(T / 128) * (512 / 128), 256, 0, stream>>>(Xb, vwT, Vt, T, 512, HIDDEN, 1);

  rope_kernel<<<(T * NHEADS * 64 + 255) / 256, 256, 0, stream>>>(Qb, pos, T, NHEADS);
  rope_kernel<<<(T * NKV * 64 + 255) / 256, 256, 0, stream>>>(Kb, pos, T, NKV);

  attn_kernel<<<(T / 64) * NHEADS, 256, 0, stream>>>(Qb, Kb, Vt, pos, cu, Qb, T, B);

  // O-projection (fp32 out), grid 256
  gemm256<<<(T / 256) * (HIDDEN / 256), 512, 0, stream>>>(Qb, owT, out, T, HIDDEN, HIDDEN, 2);
}